// Round 6
// baseline (553.142 us; speedup 1.0000x reference)
//
#include <hip/hip_runtime.h>
#include <cstdint>
#include <cstddef>

typedef unsigned int u32;
typedef unsigned short u16;

#define NB 64
#define DIN 512
#define UNITS 1024
#define TOPICS 20
#define VOCAB 32000
#define NS_OFF ((size_t)NB * TOPICS * VOCAB)
#define ESV_PART ((size_t)NB * VOCAB)    // floats per k-partial buffer

typedef __attribute__((ext_vector_type(8))) short s16x8;
typedef __attribute__((ext_vector_type(4))) float f32x4;

// ---------- bf16 helpers ----------
__device__ __forceinline__ float bf2f(u16 h) {
    union { u32 u; float f; } c; c.u = ((u32)h) << 16; return c.f;
}
__device__ __forceinline__ u16 f2bf(float f) {
    union { float f; u32 u; } c; c.f = f;
    u32 r = c.u + 0x7FFFu + ((c.u >> 16) & 1u);   // RNE
    return (u16)(r >> 16);
}
template<bool F32>
__device__ __forceinline__ float ldv(const void* p, size_t i) {
    if constexpr (F32) return ((const float*)p)[i];
    else return bf2f(((const u16*)p)[i]);
}
__device__ __forceinline__ float ldr(const void* p, size_t i, bool f32) {
    return f32 ? ((const float*)p)[i] : bf2f(((const u16*)p)[i]);
}

// ---------- threefry2x32-20, key (0,42), partitionable counts (0,i) ----------
__device__ __forceinline__ u32 threefry_bits_partitionable(u32 i) {
    const u32 ks0 = 0u, ks1 = 42u, ks2 = 0u ^ 42u ^ 0x1BD11BDAu;
    u32 x0 = 0u + ks0, x1 = i + ks1;
#define TF_R(r) { x0 += x1; x1 = (x1 << r) | (x1 >> (32 - r)); x1 ^= x0; }
    TF_R(13) TF_R(15) TF_R(26) TF_R(6)
    x0 += ks1; x1 += ks2 + 1u;
    TF_R(17) TF_R(29) TF_R(16) TF_R(24)
    x0 += ks2; x1 += ks0 + 2u;
    TF_R(13) TF_R(15) TF_R(26) TF_R(6)
    x0 += ks0; x1 += ks1 + 3u;
    TF_R(17) TF_R(29) TF_R(16) TF_R(24)
    x0 += ks1; x1 += ks2 + 4u;
    TF_R(13) TF_R(15) TF_R(26) TF_R(6)
    x0 += ks2; x1 += ks0 + 5u;
#undef TF_R
    return x0 ^ x1;
}

// ---------- init: self-detect dtype, eb = exp(beta), zero lsum, publish flag ----------
__global__ __launch_bounds__(256)
void k_init(const void* __restrict__ beta, int* __restrict__ flag,
            float* __restrict__ lsum, float* __restrict__ eb) {
    int tid = threadIdx.x, lane = tid & 63, w = tid >> 6;
    __shared__ int cnt_s[4];
    int cnt = 0;
    const u32* braw = (const u32*)beta;
    for (int i = tid; i < 1024; i += 256) {
        u32 x = braw[i];
        u32 e = (x >> 7) & 0xFFu;
        cnt += (e >= 110u && e <= 132u) ? 1 : 0;
    }
    for (int off = 32; off; off >>= 1) cnt += __shfl_down(cnt, off, 64);
    if (lane == 0) cnt_s[w] = cnt;
    __syncthreads();
    int total = cnt_s[0] + cnt_s[1] + cnt_s[2] + cnt_s[3];
    bool f32 = total < 512;

    size_t base = (size_t)blockIdx.x * 2000;
    for (int i = tid; i < 2000; i += 256)
        eb[base + i] = __expf(ldr(beta, base + i, f32));

    if (blockIdx.x == 0) {
        for (int i = tid; i < NB * TOPICS; i += 256) lsum[i] = 0.f;
        if (tid == 0) flag[0] = f32 ? 1 : 0;
    }
}

// ---------- A: next_state = x@Wxh + h@Whh ----------
template<bool F32>
__device__ void state_body(const void* xin, const void* h0, const void* Wxh,
                           const void* Whh, float* ns_f32, void* dout) {
    __shared__ float lx[DIN + UNITS];
    int b = blockIdx.x >> 2;
    int u = ((blockIdx.x & 3) << 8) | threadIdx.x;
    for (int i = threadIdx.x; i < DIN; i += 256)
        lx[i] = ldv<F32>(xin, (size_t)b * DIN + i);
    for (int i = threadIdx.x; i < UNITS; i += 256)
        lx[DIN + i] = ldv<F32>(h0, (size_t)b * UNITS + i);
    __syncthreads();
    float acc = 0.f;
#pragma unroll 8
    for (int k = 0; k < DIN; ++k)   acc += lx[k]       * ldv<F32>(Wxh, (size_t)k * UNITS + u);
#pragma unroll 8
    for (int k = 0; k < UNITS; ++k) acc += lx[DIN + k] * ldv<F32>(Whh, (size_t)k * UNITS + u);
    int idx = b * UNITS + u;
    ns_f32[idx] = acc;
    if constexpr (F32) ((float*)dout)[NS_OFF + idx] = acc;
    else               ((u16*)dout)[NS_OFF + idx]   = f2bf(acc);
}
__global__ __launch_bounds__(256)
void k_state(const int* __restrict__ flag, const void* xin, const void* h0,
             const void* Wxh, const void* Whh,
             float* __restrict__ ns_f32, void* dout) {
    if (*flag) state_body<true>(xin, h0, Wxh, Whh, ns_f32, dout);
    else       state_body<false>(xin, h0, Wxh, Whh, ns_f32, dout);
}

// ---------- B: coeff_b = 1 - bernoulli_sample ----------
template<bool F32>
__device__ void bern_body(const float* ns, const void* bk, float* coeff) {
    int b = blockIdx.x, lane = threadIdx.x;
    float s = 0.f;
#pragma unroll
    for (int i = 0; i < UNITS / 64; ++i) {
        int k = lane + (i << 6);
        s += ns[b * UNITS + k] * ldv<F32>(bk, k);
    }
    for (int off = 32; off; off >>= 1) s += __shfl_down(s, off, 64);
    if (lane == 0) {
        float sp = log1pf(expf(s));              // softplus
        float p  = 1.f / (1.f + expf(-sp));      // sigmoid
        u32 bits = threefry_bits_partitionable((u32)b);
        union { u32 u; float f; } c; c.u = (bits >> 9) | 0x3f800000u;
        float uni = c.f - 1.0f;
        coeff[b] = (uni < p) ? 0.f : 1.f;        // (1 - sample)
    }
}
__global__ __launch_bounds__(64)
void k_bern(const int* __restrict__ flag, const float* __restrict__ ns,
            const void* bk, float* __restrict__ coeff) {
    if (*flag) bern_body<true>(ns, bk, coeff);
    else       bern_body<false>(ns, bk, coeff);
}

// ============================================================================
// C: logit partials. esv4[kb][b][v] = ns[b][kb*256:(kb+1)*256] @ Wv[...][v]
//
// ROUND-6 CHANGE (discriminating experiment): B staged via PLAIN
// global_load_dwordx4 -> VGPR -> ds_write_b128 (NOT global_load_lds).
// All four prior rounds topped out at 0.39-0.65 TB/s; r1/r2 were
// occupancy/latency-confounded, r4/r5 used the LDS-DMA path. Hypothesis:
// the per-CU LDS-DMA queue caps in-flight bytes (~0.6 TB/s GPU-wide);
// plain loads (the m13 6.3 TB/s µbench path) don't. 2 reg-sets x 4
// loads/thread in flight, counted vmcnt(4) (0 only at tail), 2 raw
// barriers/step, 8 steps of k=32.
//   LDS exactly 65536 B (r5's 66560 dropped to 1 block/CU = the regression):
//     A 32KB [64 rows][32 chunks], slot = c ^ (row&7) (16B XOR within the
//       128B bank period -> frag ds_read_b128 hits the 8-access/bank floor)
//     B 2 x 16KB [32 k][256 v] linear, 16B-chunk source-XOR c^(k>>3)
//       (same involution read-side, verified correct in r5)
// f32 path: session-verified VALU tile, shares smem. Downstream (4-partial
// sum + exp in k_sum/k_write) unchanged from r5 (passed).
// ============================================================================
#define PAD 68
#define SV_AB 32768                       // A bytes
#define SV_BB 16384                       // one B stage
#define SV_SMEM_BYTES (SV_AB + 2 * SV_BB) // 65536 exactly -> 2 blocks/CU

__device__ void sv_mfma_body(const short* __restrict__ ns16,
                             const short* __restrict__ Wv,
                             float* __restrict__ esv4, char* smem, int pos) {
    short* As = (short*)smem;
    const int tid  = threadIdx.x;
    const int lane = tid & 63;
    const int wn   = tid >> 6;       // wave 0..3
    const int g    = lane >> 4;      // k-group 0..3
    const int l15  = lane & 15;

    const int vb = pos % 125, kb = pos / 125;
    const int v0 = vb * 256;
    const int kbase0 = kb * 256;

    // ---- A one-time stage: [64 rows][32 chunks], chunk slot = c^(row&7) ----
#pragma unroll
    for (int j = 0; j < 8; ++j) {
        int idx = j * 256 + tid;          // 2048 chunks of 16B
        int row = idx >> 5, c = idx & 31;
        *(s16x8*)&As[row * 256 + ((c ^ (row & 7)) << 3)] =
            *(const s16x8*)&ns16[(size_t)row * UNITS + kbase0 + (c << 3)];
    }

    // ---- B reg-staged pipeline ----
    float4 rA[4], rB[4];
    auto loadB = [&](int t, float4* r) {
        int kbase = kbase0 + t * 32;
#pragma unroll
        for (int p = 0; p < 4; ++p) {
            int idx = p * 256 + wn * 64 + lane;
            int k = idx >> 5, c = idx & 31;
            r[p] = *(const float4*)(Wv + (size_t)(kbase + k) * VOCAB + v0
                                    + ((c ^ (k >> 3)) << 3));
        }
    };
    auto writeB = [&](int t, const float4* r) {
        float4* dst = (float4*)(smem + SV_AB + (t & 1) * SV_BB);
#pragma unroll
        for (int p = 0; p < 4; ++p)
            dst[p * 256 + wn * 64 + lane] = r[p];
    };

    f32x4 acc[4][4];
#pragma unroll
    for (int m = 0; m < 4; ++m)
#pragma unroll
        for (int n = 0; n < 4; ++n) acc[m][n] = (f32x4){0.f, 0.f, 0.f, 0.f};

    auto computeT = [&](int t) {
        const short* Bs = (const short*)(smem + SV_AB + (t & 1) * SV_BB);
        s16x8 af[4];
#pragma unroll
        for (int mf = 0; mf < 4; ++mf)
            af[mf] = *(const s16x8*)&As[(mf * 16 + l15) * 256
                                        + (((t * 4 + g) ^ (l15 & 7)) << 3)];
#pragma unroll
        for (int nf = 0; nf < 4; ++nf) {
            int col = wn * 64 + nf * 16 + l15;
            int b0  = (((col >> 3) ^ g) << 3) + (col & 7);
            s16x8 bf;
#pragma unroll
            for (int e = 0; e < 8; ++e)
                bf[e] = Bs[(g * 8 + e) * 256 + b0];
#pragma unroll
            for (int mf = 0; mf < 4; ++mf)
                acc[mf][nf] = __builtin_amdgcn_mfma_f32_16x16x32_bf16(
                                  af[mf], bf, acc[mf][nf], 0, 0, 0);
        }
    };

    // prologue: stages 0,1 issued; write stage 0; A + B0 visible after barrier
    loadB(0, rA);
    loadB(1, rB);
    asm volatile("s_waitcnt vmcnt(4)" ::: "memory");   // stage 0 regs ready
    writeB(0, rA);
    asm volatile("s_waitcnt lgkmcnt(0)" ::: "memory"); // A + B0 writes done
    __builtin_amdgcn_s_barrier();

    // per step: [issue t+2] | bar#1 (end compute t-1) | vmcnt -> t+1 regs |
    //           write t+1 | lgkm | bar#2 | compute t.  vmcnt never 0 till tail.
#define SV_STEP(T, LSET, WSET, VM)                                        \
    if ((T) + 2 <= 7) loadB((T) + 2, LSET);                               \
    __builtin_amdgcn_s_barrier();                                         \
    asm volatile("s_waitcnt vmcnt(" #VM ")" ::: "memory");                \
    if ((T) + 1 <= 7) writeB((T) + 1, WSET);                              \
    asm volatile("s_waitcnt lgkmcnt(0)" ::: "memory");                    \
    __builtin_amdgcn_s_barrier();                                         \
    computeT(T);

    SV_STEP(0, rA, rB, 4)
    SV_STEP(1, rB, rA, 4)
    SV_STEP(2, rA, rB, 4)
    SV_STEP(3, rB, rA, 4)
    SV_STEP(4, rA, rB, 4)
    SV_STEP(5, rB, rA, 4)
    SV_STEP(6, rA, rB, 0)
    computeT(7);                       // buf1 written+barriered at step 6
#undef SV_STEP

    // ---- epilogue: raw logit partial. C/D: row=(lane>>4)*4+r, col=l15 ----
    float* dst = esv4 + (size_t)kb * ESV_PART + v0;
#pragma unroll
    for (int mf = 0; mf < 4; ++mf)
#pragma unroll
        for (int nf = 0; nf < 4; ++nf) {
            int col = wn * 64 + nf * 16 + l15;
#pragma unroll
            for (int r = 0; r < 4; ++r) {
                int b = mf * 16 + (lane >> 4) * 4 + r;
                dst[(size_t)b * VOCAB + col] = acc[mf][nf][r];
            }
        }
}

__device__ void sv_f32_body(const float* __restrict__ ns, const float* __restrict__ Wv,
                            float* __restrict__ esv4, float* As, float* Bs, int pos) {
    int tid = threadIdx.x;
    int vt = tid & 7;           // 8 v-threads x 8 v = 64 v
    int bg = tid >> 3;          // 32 groups x 2 b = 64 b
    int v0 = pos * 64;
    float acc[2][8];
#pragma unroll
    for (int r = 0; r < 2; ++r)
#pragma unroll
        for (int j = 0; j < 8; ++j) acc[r][j] = 0.f;

    for (int k0 = 0; k0 < UNITS; k0 += 64) {
        __syncthreads();
        for (int e = tid; e < 1024; e += 256) {      // stage A: ns[64b][64k]
            int row = e >> 4, c4 = e & 15;
            *(float4*)&As[row * PAD + c4 * 4] =
                *(const float4*)&ns[row * UNITS + k0 + c4 * 4];
        }
        for (int e = tid; e < 1024; e += 256) {      // stage B: Wv[64k][64v]
            int row = e >> 4, c4 = e & 15;
            *(float4*)&Bs[row * PAD + c4 * 4] =
                *(const float4*)(Wv + (size_t)(k0 + row) * VOCAB + v0 + c4 * 4);
        }
        __syncthreads();
#pragma unroll 4
        for (int u = 0; u < 64; u += 4) {
            float4 a0 = *(float4*)&As[(bg * 2 + 0) * PAD + u];
            float4 a1 = *(float4*)&As[(bg * 2 + 1) * PAD + u];
            float aa0[4] = {a0.x, a0.y, a0.z, a0.w};
            float aa1[4] = {a1.x, a1.y, a1.z, a1.w};
#pragma unroll
            for (int uu = 0; uu < 4; ++uu) {
                float4 b0 = *(float4*)&Bs[(u + uu) * PAD + vt * 8];
                float4 b1 = *(float4*)&Bs[(u + uu) * PAD + vt * 8 + 4];
                float bb[8] = {b0.x, b0.y, b0.z, b0.w, b1.x, b1.y, b1.z, b1.w};
#pragma unroll
                for (int j = 0; j < 8; ++j) {
                    acc[0][j] = fmaf(aa0[uu], bb[j], acc[0][j]);
                    acc[1][j] = fmaf(aa1[uu], bb[j], acc[1][j]);
                }
            }
        }
    }
    // raw logits to part 0 (exp applied downstream)
#pragma unroll
    for (int r = 0; r < 2; ++r) {
        float4 e0 = {acc[r][0], acc[r][1], acc[r][2], acc[r][3]};
        float4 e1 = {acc[r][4], acc[r][5], acc[r][6], acc[r][7]};
        float* dst = esv4 + (size_t)(bg * 2 + r) * VOCAB + v0 + vt * 8;
        *(float4*)dst = e0;
        *(float4*)(dst + 4) = e1;
    }
}

__global__ __launch_bounds__(256)
void k_sv(const int* __restrict__ flag, const float* __restrict__ ns,
          const void* Wv, const void* dout, float* __restrict__ esv4) {
    __shared__ __align__(16) char smem[SV_SMEM_BYTES];
    // bijective XCD-chunked remap: same-XCD blocks get consecutive pos
    int lin = blockIdx.x;                     // 0..499
    int xcd = lin & 7, idx = lin >> 3;
    int pos = (xcd < 4) ? xcd * 63 + idx : 252 + (xcd - 4) * 62 + idx;
    if (*flag) {
        float* As = (float*)smem;
        sv_f32_body(ns, (const float*)Wv, esv4, As, As + 64 * PAD, pos);
    } else {
        sv_mfma_body((const short*)dout + NS_OFF, (const short*)Wv, esv4, smem, pos);
    }
}

// ---------- D1: lsum[b][t] = sum_v exp(sum_kb p_kb) * (c ? eb[t][v] : 1) ----------
__global__ __launch_bounds__(256)
void k_sum(const int* __restrict__ flag, const float* __restrict__ esv4,
           const float* __restrict__ eb, const float* __restrict__ coeff,
           float* __restrict__ lsum) {
    int b = blockIdx.y, tid = threadIdx.x;
    bool f32 = (*flag != 0);
    float c = coeff[b];
    const float4* P0 = (const float4*)(esv4 + (size_t)b * VOCAB);
    const float4* P1 = (const float4*)(esv4 + ESV_PART + (size_t)b * VOCAB);
    const float4* P2 = (const float4*)(esv4 + 2 * ESV_PART + (size_t)b * VOCAB);
    const float4* P3 = (const float4*)(esv4 + 3 * ESV_PART + (size_t)b * VOCAB);
    int i0 = blockIdx.x * 256 + tid;
    __shared__ float red[4][TOPICS];
    int lane = tid & 63, w = tid >> 6;

    if (c != 0.f) {
        float acc[TOPICS];
#pragma unroll
        for (int t = 0; t < TOPICS; ++t) acc[t] = 0.f;
        for (int i = i0; i < VOCAB / 4; i += 4096) {
            float4 q = P0[i];
            if (!f32) {
                float4 a = P1[i], d = P2[i], h = P3[i];
                q.x += a.x + d.x + h.x; q.y += a.y + d.y + h.y;
                q.z += a.z + d.z + h.z; q.w += a.w + d.w + h.w;
            }
            float4 e;
            e.x = __expf(q.x); e.y = __expf(q.y);
            e.z = __expf(q.z); e.w = __expf(q.w);
#pragma unroll
            for (int t = 0; t < TOPICS; ++t) {
                float4 g = *(const float4*)(eb + (size_t)t * VOCAB + i * 4);
                acc[t] += e.x * g.x + e.y * g.y + e.z * g.z + e.w * g.w;
            }
        }
#pragma unroll
        for (int t = 0; t < TOPICS; ++t) {
            float v = acc[t];
            for (int off = 32; off; off >>= 1) v += __shfl_down(v, off, 64);
            if (lane == 0) red[w][t] = v;
        }
        __syncthreads();
        if (tid < TOPICS) {
            float s = red[0][tid] + red[1][tid] + red[2][tid] + red[3][tid];
            atomicAdd(&lsum[b * TOPICS + tid], s);
        }
    } else {
        float a = 0.f;
        for (int i = i0; i < VOCAB / 4; i += 4096) {
            float4 q = P0[i];
            if (!f32) {
                float4 x = P1[i], d = P2[i], h = P3[i];
                q.x += x.x + d.x + h.x; q.y += x.y + d.y + h.y;
                q.z += x.z + d.z + h.z; q.w += x.w + d.w + h.w;
            }
            a += __expf(q.x) + __expf(q.y) + __expf(q.z) + __expf(q.w);
        }
        for (int off = 32; off; off >>= 1) a += __shfl_down(a, off, 64);
        if (lane == 0) red[w][0] = a;
        __syncthreads();
        if (tid < TOPICS) {
            float s = red[0][0] + red[1][0] + red[2][0] + red[3][0];
            atomicAdd(&lsum[b * TOPICS + tid], s);
        }
    }
}

// ---------- D2: out[b][t][v] = exp(sum_kb p_kb) * (c ? eb[t][v] : 1) / lsum[b][t] ----------
template<bool F32>
__device__ void write_body(const float* esv4, const float* eb, const float* coeff,
                           const float* lsum, void* dout) {
    int b = blockIdx.y, tid = threadIdx.x;
    int v0 = blockIdx.x * 2048 + tid * 8;
    if (v0 >= VOCAB) return;
    float c = coeff[b];
    const float* er = esv4 + (size_t)b * VOCAB + v0;
    float4 q0 = *(const float4*)er;
    float4 q1 = *(const float4*)(er + 4);
    if constexpr (!F32) {            // bf16 path: sum 4 k-partials
#pragma unroll
        for (int p = 1; p < 4; ++p) {
            float4 a0 = *(const float4*)(er + p * ESV_PART);
            float4 a1 = *(const float4*)(er + p * ESV_PART + 4);
            q0.x += a0.x; q0.y += a0.y; q0.z += a0.z; q0.w += a0.w;
            q1.x += a1.x; q1.y += a1.y; q1.z += a1.z; q1.w += a1.w;
        }
    }
    float4 e0, e1;
    e0.x = __expf(q0.x); e0.y = __expf(q0.y); e0.z = __expf(q0.z); e0.w = __expf(q0.w);
    e1.x = __expf(q1.x); e1.y = __expf(q1.y); e1.z = __expf(q1.z); e1.w = __expf(q1.w);
#pragma unroll 4
    for (int t = 0; t < TOPICS; ++t) {
        float inv = 1.0f / lsum[b * TOPICS + t];
        float o0, o1, o2, o3, o4, o5, o6, o7;
        if (c != 0.f) {
            const float* gr = eb + (size_t)t * VOCAB + v0;
            float4 g0 = *(const float4*)gr;
            float4 g1 = *(const float4*)(gr + 4);
            o0 = e0.x * g0.x * inv; o1 = e0.y * g0.y * inv;
            o2 = e0.z * g0.z * inv; o3 = e0.w * g0.w * inv;
            o4 = e1.x * g1.x * inv; o5 = e1.y * g1.y * inv;
            o6 = e1.z * g1.z * inv; o7 = e1.w * g1.w * inv;
        } else {
            o0 = e0.x * inv; o1 = e0.y * inv; o2 = e0.z * inv; o3 = e0.w * inv;
            o4 = e1.x * inv; o5 = e1.y * inv; o6 = e1.z * inv; o7 = e1.w * inv;
        }
        size_t off = (size_t)b * TOPICS * VOCAB + (size_t)t * VOCAB + v0;
        if constexpr (F32) {
            float4 s0 = {o0, o1, o2, o3}, s1 = {o4, o5, o6, o7};
            *(float4*)((float*)dout + off) = s0;
            *(float4*)((float*)dout + off + 4) = s1;
        } else {
            uint4 st;
            st.x = (u32)f2bf(o0) | ((u32)f2bf(o1) << 16);
            st.y = (u32)f2bf(o2) | ((u32)f2bf(o3) << 16);
            st.z = (u32)f2bf(o4) | ((u32)f2bf(o5) << 16);
            st.w = (u32)f2bf(o6) | ((u32)f2bf(o7) << 16);
            *(uint4*)((u16*)dout + off) = st;
        }
    }
}
__global__ __launch_bounds__(256)
void k_write(const int* __restrict__ flag, const float* __restrict__ esv4,
             const float* __restrict__ eb, const float* __restrict__ coeff,
             const float* __restrict__ lsum, void* dout) {
    if (*flag) write_body<true>(esv4, eb, coeff, lsum, dout);
    else       write_body<false>(esv4, eb, coeff, lsum, dout);
}

extern "C" void kernel_launch(void* const* d_in, const int* in_sizes, int n_in,
                              void* d_out, int out_size, void* d_ws, size_t ws_size,
                              hipStream_t stream) {
    const void* xin  = d_in[0];
    const void* h0   = d_in[1];
    const void* Wxh  = d_in[2];
    const void* Whh  = d_in[3];
    const void* bk   = d_in[4];
    const void* Wv   = d_in[5];
    const void* beta = d_in[6];

    char* ws = (char*)d_ws;
    int*   flag   = (int*)  (ws + 0);
    float* coeff  = (float*)(ws + 256);
    float* lsum   = (float*)(ws + 1024);      // 1280 f -> ends 6144
    float* ns_f32 = (float*)(ws + 8192);      // 256 KiB -> ends 270336
    float* eb     = (float*)(ws + 270336);    // 2.56 MB -> ends 2830336
    float* esv4   = (float*)(ws + 2830336);   // 4 x 8.192 MB -> ends 35598336

    k_init <<<320, 256, 0, stream>>>(beta, flag, lsum, eb);
    k_state<<<256, 256, 0, stream>>>(flag, xin, h0, Wxh, Whh, ns_f32, d_out);
    k_bern <<<64, 64, 0, stream>>>(flag, ns_f32, bk, coeff);
    k_sv   <<<500, 256, 0, stream>>>(flag, ns_f32, Wv, d_out, esv4);
    k_sum  <<<dim3(16, 64), 256, 0, stream>>>(flag, esv4, eb, coeff, lsum);
    k_write<<<dim3(16, 64), 256, 0, stream>>>(flag, esv4, eb, coeff, lsum, d_out);
}

// Round 7
// 483.709 us; speedup vs baseline: 1.1435x; 1.1435x over previous
//
#include <hip/hip_runtime.h>
#include <cstdint>
#include <cstddef>

typedef unsigned int u32;
typedef unsigned short u16;

#define NB 64
#define DIN 512
#define UNITS 1024
#define TOPICS 20
#define VOCAB 32000
#define NS_OFF ((size_t)NB * TOPICS * VOCAB)
#define ESV_PART ((size_t)NB * VOCAB)    // floats per k-partial buffer

typedef __attribute__((ext_vector_type(8))) short s16x8;
typedef __attribute__((ext_vector_type(4))) float f32x4;

// ---------- bf16 helpers ----------
__device__ __forceinline__ float bf2f(u16 h) {
    union { u32 u; float f; } c; c.u = ((u32)h) << 16; return c.f;
}
__device__ __forceinline__ u16 f2bf(float f) {
    union { float f; u32 u; } c; c.f = f;
    u32 r = c.u + 0x7FFFu + ((c.u >> 16) & 1u);   // RNE
    return (u16)(r >> 16);
}
template<bool F32>
__device__ __forceinline__ float ldv(const void* p, size_t i) {
    if constexpr (F32) return ((const float*)p)[i];
    else return bf2f(((const u16*)p)[i]);
}
__device__ __forceinline__ float ldr(const void* p, size_t i, bool f32) {
    return f32 ? ((const float*)p)[i] : bf2f(((const u16*)p)[i]);
}

// ---------- threefry2x32-20, key (0,42), partitionable counts (0,i) ----------
__device__ __forceinline__ u32 threefry_bits_partitionable(u32 i) {
    const u32 ks0 = 0u, ks1 = 42u, ks2 = 0u ^ 42u ^ 0x1BD11BDAu;
    u32 x0 = 0u + ks0, x1 = i + ks1;
#define TF_R(r) { x0 += x1; x1 = (x1 << r) | (x1 >> (32 - r)); x1 ^= x0; }
    TF_R(13) TF_R(15) TF_R(26) TF_R(6)
    x0 += ks1; x1 += ks2 + 1u;
    TF_R(17) TF_R(29) TF_R(16) TF_R(24)
    x0 += ks2; x1 += ks0 + 2u;
    TF_R(13) TF_R(15) TF_R(26) TF_R(6)
    x0 += ks0; x1 += ks1 + 3u;
    TF_R(17) TF_R(29) TF_R(16) TF_R(24)
    x0 += ks1; x1 += ks2 + 4u;
    TF_R(13) TF_R(15) TF_R(26) TF_R(6)
    x0 += ks2; x1 += ks0 + 5u;
#undef TF_R
    return x0 ^ x1;
}

// ---------- init: self-detect dtype, eb = exp(beta), zero lsum, publish flag ----------
__global__ __launch_bounds__(256)
void k_init(const void* __restrict__ beta, int* __restrict__ flag,
            float* __restrict__ lsum, float* __restrict__ eb) {
    int tid = threadIdx.x, lane = tid & 63, w = tid >> 6;
    __shared__ int cnt_s[4];
    int cnt = 0;
    const u32* braw = (const u32*)beta;
    for (int i = tid; i < 1024; i += 256) {
        u32 x = braw[i];
        u32 e = (x >> 7) & 0xFFu;
        cnt += (e >= 110u && e <= 132u) ? 1 : 0;
    }
    for (int off = 32; off; off >>= 1) cnt += __shfl_down(cnt, off, 64);
    if (lane == 0) cnt_s[w] = cnt;
    __syncthreads();
    int total = cnt_s[0] + cnt_s[1] + cnt_s[2] + cnt_s[3];
    bool f32 = total < 512;

    size_t base = (size_t)blockIdx.x * 2000;
    for (int i = tid; i < 2000; i += 256)
        eb[base + i] = __expf(ldr(beta, base + i, f32));

    if (blockIdx.x == 0) {
        for (int i = tid; i < NB * TOPICS; i += 256) lsum[i] = 0.f;
        if (tid == 0) flag[0] = f32 ? 1 : 0;
    }
}

// ---------- A: next_state = x@Wxh + h@Whh ----------
template<bool F32>
__device__ void state_body(const void* xin, const void* h0, const void* Wxh,
                           const void* Whh, float* ns_f32, void* dout) {
    __shared__ float lx[DIN + UNITS];
    int b = blockIdx.x >> 2;
    int u = ((blockIdx.x & 3) << 8) | threadIdx.x;
    for (int i = threadIdx.x; i < DIN; i += 256)
        lx[i] = ldv<F32>(xin, (size_t)b * DIN + i);
    for (int i = threadIdx.x; i < UNITS; i += 256)
        lx[DIN + i] = ldv<F32>(h0, (size_t)b * UNITS + i);
    __syncthreads();
    float acc = 0.f;
#pragma unroll 8
    for (int k = 0; k < DIN; ++k)   acc += lx[k]       * ldv<F32>(Wxh, (size_t)k * UNITS + u);
#pragma unroll 8
    for (int k = 0; k < UNITS; ++k) acc += lx[DIN + k] * ldv<F32>(Whh, (size_t)k * UNITS + u);
    int idx = b * UNITS + u;
    ns_f32[idx] = acc;
    if constexpr (F32) ((float*)dout)[NS_OFF + idx] = acc;
    else               ((u16*)dout)[NS_OFF + idx]   = f2bf(acc);
}
__global__ __launch_bounds__(256)
void k_state(const int* __restrict__ flag, const void* xin, const void* h0,
             const void* Wxh, const void* Whh,
             float* __restrict__ ns_f32, void* dout) {
    if (*flag) state_body<true>(xin, h0, Wxh, Whh, ns_f32, dout);
    else       state_body<false>(xin, h0, Wxh, Whh, ns_f32, dout);
}

// ---------- B: coeff_b = 1 - bernoulli_sample ----------
template<bool F32>
__device__ void bern_body(const float* ns, const void* bk, float* coeff) {
    int b = blockIdx.x, lane = threadIdx.x;
    float s = 0.f;
#pragma unroll
    for (int i = 0; i < UNITS / 64; ++i) {
        int k = lane + (i << 6);
        s += ns[b * UNITS + k] * ldv<F32>(bk, k);
    }
    for (int off = 32; off; off >>= 1) s += __shfl_down(s, off, 64);
    if (lane == 0) {
        float sp = log1pf(expf(s));              // softplus
        float p  = 1.f / (1.f + expf(-sp));      // sigmoid
        u32 bits = threefry_bits_partitionable((u32)b);
        union { u32 u; float f; } c; c.u = (bits >> 9) | 0x3f800000u;
        float uni = c.f - 1.0f;
        coeff[b] = (uni < p) ? 0.f : 1.f;        // (1 - sample)
    }
}
__global__ __launch_bounds__(64)
void k_bern(const int* __restrict__ flag, const float* __restrict__ ns,
            const void* bk, float* __restrict__ coeff) {
    if (*flag) bern_body<true>(ns, bk, coeff);
    else       bern_body<false>(ns, bk, coeff);
}

// ============================================================================
// C: logit partials. esv4[kb][b][v] = ns[b][kb*256:(kb+1)*256] @ Wv[...][v]
//
// ROUND-7: concurrency-first rebuild of the bf16 path.
//  * A-fragments come STRAIGHT FROM GLOBAL each step (ns = 128KB, L1/L2-hot;
//    per-wave 64 lanes read 64 unique 16B chunks). No A LDS, no A stage.
//  * LDS = B double-buffer only: 2 x 16KB (+ f32 path needs 34816 total).
//    r6's 81920-byte allocation (vs 65536 declared) collapsed us to 1
//    block/CU; suspect = address-taken float4 arrays in lambdas. This round:
//    NAMED register sets, macros only, nothing address-taken.
//  * One s_barrier per step; counted vmcnt(8) steady (A+B loads both count;
//    issue order per step = [4 B-loads, 4 A-loads], so vmcnt(8) drains
//    exactly {B(t+1), A(t)}), tail 4/0. lgkmcnt(0) after ds_writes.
//  * __launch_bounds__(256,3): 3 waves/EU -> 3 blocks/CU target, ~12 waves,
//    ~8KB in flight per wave = 3-4x r6's per-CU concurrency.
// Swizzles (verified r5/r6, absmax unchanged): B global-src chunk c^p,
// read-side slot (col>>3)^g. Downstream 4-partial sum unchanged.
// ============================================================================
#define PAD 68
#define SV_BB 16384                       // one B stage: 32k x 256v bf16
#define SV_SMEM_BYTES 34816               // f32 path needs 2*64*PAD*4 = 34816

__device__ void sv_mfma_body(const short* __restrict__ ns16,
                             const short* __restrict__ Wv,
                             float* __restrict__ esv4, char* smem, int pos) {
    const int tid  = threadIdx.x;
    const int lane = tid & 63;
    const int wn   = tid >> 6;       // wave 0..3
    const int g    = lane >> 4;      // k-group 0..3
    const int l15  = lane & 15;

    const int vb = pos % 125, kb = pos / 125;
    const int v0 = vb * 256;
    const int kbase0 = kb * 256;

    // B source pointers: load p reads k-row p*8+(tid>>5), 16B chunk (tid&31)^p
    const int w5 = tid >> 5, c31 = tid & 31;
    const short* bs0 = Wv + (size_t)(kbase0 +  0 + w5) * VOCAB + v0 + ((c31 ^ 0) << 3);
    const short* bs1 = Wv + (size_t)(kbase0 +  8 + w5) * VOCAB + v0 + ((c31 ^ 1) << 3);
    const short* bs2 = Wv + (size_t)(kbase0 + 16 + w5) * VOCAB + v0 + ((c31 ^ 2) << 3);
    const short* bs3 = Wv + (size_t)(kbase0 + 24 + w5) * VOCAB + v0 + ((c31 ^ 3) << 3);
    // A source pointers: frag mf reads row mf*16+l15, k-run kbase0+t*32+g*8
    const short* as0 = ns16 + (size_t)(l15     ) * UNITS + kbase0 + g * 8;
    const short* as1 = ns16 + (size_t)(l15 + 16) * UNITS + kbase0 + g * 8;
    const short* as2 = ns16 + (size_t)(l15 + 32) * UNITS + kbase0 + g * 8;
    const short* as3 = ns16 + (size_t)(l15 + 48) * UNITS + kbase0 + g * 8;

    float4 bE0, bE1, bE2, bE3;           // B even set (holds B(t), t even)
    float4 bO0, bO1, bO2, bO3;           // B odd set
    s16x8  aE0, aE1, aE2, aE3;           // A even set
    s16x8  aO0, aO1, aO2, aO3;           // A odd set

    f32x4 acc[4][4];
#pragma unroll
    for (int m = 0; m < 4; ++m)
#pragma unroll
        for (int n = 0; n < 4; ++n) acc[m][n] = (f32x4){0.f, 0.f, 0.f, 0.f};

#define LOADB(T, R0, R1, R2, R3) {                                        \
    size_t ko = (size_t)(T) * 32 * VOCAB;                                 \
    R0 = *(const float4*)(bs0 + ko); R1 = *(const float4*)(bs1 + ko);     \
    R2 = *(const float4*)(bs2 + ko); R3 = *(const float4*)(bs3 + ko); }
#define LOADA(T, A0, A1, A2, A3) {                                        \
    int ko = (T) * 32;                                                    \
    A0 = *(const s16x8*)(as0 + ko); A1 = *(const s16x8*)(as1 + ko);       \
    A2 = *(const s16x8*)(as2 + ko); A3 = *(const s16x8*)(as3 + ko); }
#define WRITEB(BUF, R0, R1, R2, R3) {                                     \
    float4* d = (float4*)(smem + (BUF) * SV_BB);                          \
    d[tid] = R0; d[256 + tid] = R1; d[512 + tid] = R2; d[768 + tid] = R3; }
#define COMPUTE(BUF, A0, A1, A2, A3) {                                    \
    const short* Bs = (const short*)(smem + (BUF) * SV_BB);               \
    _Pragma("unroll")                                                     \
    for (int nf = 0; nf < 4; ++nf) {                                      \
        int col = wn * 64 + nf * 16 + l15;                                \
        int b0  = (((col >> 3) ^ g) << 3) + (col & 7);                    \
        s16x8 bf;                                                         \
        _Pragma("unroll")                                                 \
        for (int e = 0; e < 8; ++e) bf[e] = Bs[(g * 8 + e) * 256 + b0];   \
        acc[0][nf] = __builtin_amdgcn_mfma_f32_16x16x32_bf16(A0, bf, acc[0][nf], 0, 0, 0); \
        acc[1][nf] = __builtin_amdgcn_mfma_f32_16x16x32_bf16(A1, bf, acc[1][nf], 0, 0, 0); \
        acc[2][nf] = __builtin_amdgcn_mfma_f32_16x16x32_bf16(A2, bf, acc[2][nf], 0, 0, 0); \
        acc[3][nf] = __builtin_amdgcn_mfma_f32_16x16x32_bf16(A3, bf, acc[3][nf], 0, 0, 0); } }
#define VMW(N)  asm volatile("s_waitcnt vmcnt(" #N ")" ::: "memory");
#define LGK0    asm volatile("s_waitcnt lgkmcnt(0)" ::: "memory");
#define BAR     __builtin_amdgcn_s_barrier();

    // prologue: issue B(0), A(0), B(1) -> 12 outstanding; vmcnt(8) drains B(0)
    LOADB(0, bE0, bE1, bE2, bE3)
    LOADA(0, aE0, aE1, aE2, aE3)
    LOADB(1, bO0, bO1, bO2, bO3)
    VMW(8)
    WRITEB(0, bE0, bE1, bE2, bE3)
    LGK0

    // step T: issue B(T+2),A(T+1); bar; vmcnt -> {B(T+1),A(T)} ready;
    //         write B(T+1); lgkm; compute(T).  One barrier per step.
    // T=0
    LOADB(2, bE0, bE1, bE2, bE3)  LOADA(1, aO0, aO1, aO2, aO3)
    BAR  VMW(8)  WRITEB(1, bO0, bO1, bO2, bO3)  LGK0
    COMPUTE(0, aE0, aE1, aE2, aE3)
    // T=1
    LOADB(3, bO0, bO1, bO2, bO3)  LOADA(2, aE0, aE1, aE2, aE3)
    BAR  VMW(8)  WRITEB(0, bE0, bE1, bE2, bE3)  LGK0
    COMPUTE(1, aO0, aO1, aO2, aO3)
    // T=2
    LOADB(4, bE0, bE1, bE2, bE3)  LOADA(3, aO0, aO1, aO2, aO3)
    BAR  VMW(8)  WRITEB(1, bO0, bO1, bO2, bO3)  LGK0
    COMPUTE(2, aE0, aE1, aE2, aE3)
    // T=3
    LOADB(5, bO0, bO1, bO2, bO3)  LOADA(4, aE0, aE1, aE2, aE3)
    BAR  VMW(8)  WRITEB(0, bE0, bE1, bE2, bE3)  LGK0
    COMPUTE(3, aO0, aO1, aO2, aO3)
    // T=4
    LOADB(6, bE0, bE1, bE2, bE3)  LOADA(5, aO0, aO1, aO2, aO3)
    BAR  VMW(8)  WRITEB(1, bO0, bO1, bO2, bO3)  LGK0
    COMPUTE(4, aE0, aE1, aE2, aE3)
    // T=5
    LOADB(7, bO0, bO1, bO2, bO3)  LOADA(6, aE0, aE1, aE2, aE3)
    BAR  VMW(8)  WRITEB(0, bE0, bE1, bE2, bE3)  LGK0
    COMPUTE(5, aO0, aO1, aO2, aO3)
    // T=6: no B(8); outstanding {B(7),A(6),A(7)} -> vmcnt(4) drains B(7),A(6)
    LOADA(7, aO0, aO1, aO2, aO3)
    BAR  VMW(4)  WRITEB(1, bO0, bO1, bO2, bO3)  LGK0
    COMPUTE(6, aE0, aE1, aE2, aE3)
    // T=7: bar for other waves' B(7) writes; vmcnt(0) for A(7)
    BAR  VMW(0)
    COMPUTE(7, aO0, aO1, aO2, aO3)

#undef LOADB
#undef LOADA
#undef WRITEB
#undef COMPUTE
#undef VMW
#undef LGK0
#undef BAR

    // ---- epilogue: raw logit partial. C/D: row=(lane>>4)*4+r, col=l15 ----
    float* dst = esv4 + (size_t)kb * ESV_PART + v0;
#pragma unroll
    for (int mf = 0; mf < 4; ++mf)
#pragma unroll
        for (int nf = 0; nf < 4; ++nf) {
            int col = wn * 64 + nf * 16 + l15;
#pragma unroll
            for (int r = 0; r < 4; ++r) {
                int b = mf * 16 + (lane >> 4) * 4 + r;
                dst[(size_t)b * VOCAB + col] = acc[mf][nf][r];
            }
        }
}

__device__ void sv_f32_body(const float* __restrict__ ns, const float* __restrict__ Wv,
                            float* __restrict__ esv4, float* As, float* Bs, int pos) {
    int tid = threadIdx.x;
    int vt = tid & 7;           // 8 v-threads x 8 v = 64 v
    int bg = tid >> 3;          // 32 groups x 2 b = 64 b
    int v0 = pos * 64;
    float acc[2][8];
#pragma unroll
    for (int r = 0; r < 2; ++r)
#pragma unroll
        for (int j = 0; j < 8; ++j) acc[r][j] = 0.f;

    for (int k0 = 0; k0 < UNITS; k0 += 64) {
        __syncthreads();
        for (int e = tid; e < 1024; e += 256) {      // stage A: ns[64b][64k]
            int row = e >> 4, c4 = e & 15;
            *(float4*)&As[row * PAD + c4 * 4] =
                *(const float4*)&ns[row * UNITS + k0 + c4 * 4];
        }
        for (int e = tid; e < 1024; e += 256) {      // stage B: Wv[64k][64v]
            int row = e >> 4, c4 = e & 15;
            *(float4*)&Bs[row * PAD + c4 * 4] =
                *(const float4*)(Wv + (size_t)(k0 + row) * VOCAB + v0 + c4 * 4);
        }
        __syncthreads();
#pragma unroll 4
        for (int u = 0; u < 64; u += 4) {
            float4 a0 = *(float4*)&As[(bg * 2 + 0) * PAD + u];
            float4 a1 = *(float4*)&As[(bg * 2 + 1) * PAD + u];
            float aa0[4] = {a0.x, a0.y, a0.z, a0.w};
            float aa1[4] = {a1.x, a1.y, a1.z, a1.w};
#pragma unroll
            for (int uu = 0; uu < 4; ++uu) {
                float4 b0 = *(float4*)&Bs[(u + uu) * PAD + vt * 8];
                float4 b1 = *(float4*)&Bs[(u + uu) * PAD + vt * 8 + 4];
                float bb[8] = {b0.x, b0.y, b0.z, b0.w, b1.x, b1.y, b1.z, b1.w};
#pragma unroll
                for (int j = 0; j < 8; ++j) {
                    acc[0][j] = fmaf(aa0[uu], bb[j], acc[0][j]);
                    acc[1][j] = fmaf(aa1[uu], bb[j], acc[1][j]);
                }
            }
        }
    }
    // raw logits to part 0 (exp applied downstream)
#pragma unroll
    for (int r = 0; r < 2; ++r) {
        float4 e0 = {acc[r][0], acc[r][1], acc[r][2], acc[r][3]};
        float4 e1 = {acc[r][4], acc[r][5], acc[r][6], acc[r][7]};
        float* dst = esv4 + (size_t)(bg * 2 + r) * VOCAB + v0 + vt * 8;
        *(float4*)dst = e0;
        *(float4*)(dst + 4) = e1;
    }
}

__global__ __launch_bounds__(256, 3)
void k_sv(const int* __restrict__ flag, const float* __restrict__ ns,
          const void* Wv, const void* dout, float* __restrict__ esv4) {
    __shared__ __align__(16) char smem[SV_SMEM_BYTES];
    // bijective XCD-chunked remap: same-XCD blocks get consecutive pos
    int lin = blockIdx.x;                     // 0..499
    int xcd = lin & 7, idx = lin >> 3;
    int pos = (xcd < 4) ? xcd * 63 + idx : 252 + (xcd - 4) * 62 + idx;
    if (*flag) {
        float* As = (float*)smem;
        sv_f32_body(ns, (const float*)Wv, esv4, As, As + 64 * PAD, pos);
    } else {
        sv_mfma_body((const short*)dout + NS_OFF, (const short*)Wv, esv4, smem, pos);
    }
}

// ---------- D1: lsum[b][t] = sum_v exp(sum_kb p_kb) * (c ? eb[t][v] : 1) ----------
__global__ __launch_bounds__(256)
void k_sum(const int* __restrict__ flag, const float* __restrict__ esv4,
           const float* __restrict__ eb, const float* __restrict__ coeff,
           float* __restrict__ lsum) {
    int b = blockIdx.y, tid = threadIdx.x;
    bool f32 = (*flag != 0);
    float c = coeff[b];
    const float4* P0 = (const float4*)(esv4 + (size_t)b * VOCAB);
    const float4* P1 = (const float4*)(esv4 + ESV_PART + (size_t)b * VOCAB);
    const float4* P2 = (const float4*)(esv4 + 2 * ESV_PART + (size_t)b * VOCAB);
    const float4* P3 = (const float4*)(esv4 + 3 * ESV_PART + (size_t)b * VOCAB);
    int i0 = blockIdx.x * 256 + tid;
    __shared__ float red[4][TOPICS];
    int lane = tid & 63, w = tid >> 6;

    if (c != 0.f) {
        float acc[TOPICS];
#pragma unroll
        for (int t = 0; t < TOPICS; ++t) acc[t] = 0.f;
        for (int i = i0; i < VOCAB / 4; i += 4096) {
            float4 q = P0[i];
            if (!f32) {
                float4 a = P1[i], d = P2[i], h = P3[i];
                q.x += a.x + d.x + h.x; q.y += a.y + d.y + h.y;
                q.z += a.z + d.z + h.z; q.w += a.w + d.w + h.w;
            }
            float4 e;
            e.x = __expf(q.x); e.y = __expf(q.y);
            e.z = __expf(q.z); e.w = __expf(q.w);
#pragma unroll
            for (int t = 0; t < TOPICS; ++t) {
                float4 g = *(const float4*)(eb + (size_t)t * VOCAB + i * 4);
                acc[t] += e.x * g.x + e.y * g.y + e.z * g.z + e.w * g.w;
            }
        }
#pragma unroll
        for (int t = 0; t < TOPICS; ++t) {
            float v = acc[t];
            for (int off = 32; off; off >>= 1) v += __shfl_down(v, off, 64);
            if (lane == 0) red[w][t] = v;
        }
        __syncthreads();
        if (tid < TOPICS) {
            float s = red[0][tid] + red[1][tid] + red[2][tid] + red[3][tid];
            atomicAdd(&lsum[b * TOPICS + tid], s);
        }
    } else {
        float a = 0.f;
        for (int i = i0; i < VOCAB / 4; i += 4096) {
            float4 q = P0[i];
            if (!f32) {
                float4 x = P1[i], d = P2[i], h = P3[i];
                q.x += x.x + d.x + h.x; q.y += x.y + d.y + h.y;
                q.z += x.z + d.z + h.z; q.w += x.w + d.w + h.w;
            }
            a += __expf(q.x) + __expf(q.y) + __expf(q.z) + __expf(q.w);
        }
        for (int off = 32; off; off >>= 1) a += __shfl_down(a, off, 64);
        if (lane == 0) red[w][0] = a;
        __syncthreads();
        if (tid < TOPICS) {
            float s = red[0][0] + red[1][0] + red[2][0] + red[3][0];
            atomicAdd(&lsum[b * TOPICS + tid], s);
        }
    }
}

// ---------- D2: out[b][t][v] = exp(sum_kb p_kb) * (c ? eb[t][v] : 1) / lsum[b][t] ----------
template<bool F32>
__device__ void write_body(const float* esv4, const float* eb, const float* coeff,
                           const float* lsum, void* dout) {
    int b = blockIdx.y, tid = threadIdx.x;
    int v0 = blockIdx.x * 2048 + tid * 8;
    if (v0 >= VOCAB) return;
    float c = coeff[b];
    const float* er = esv4 + (size_t)b * VOCAB + v0;
    float4 q0 = *(const float4*)er;
    float4 q1 = *(const float4*)(er + 4);
    if constexpr (!F32) {            // bf16 path: sum 4 k-partials
#pragma unroll
        for (int p = 1; p < 4; ++p) {
            float4 a0 = *(const float4*)(er + p * ESV_PART);
            float4 a1 = *(const float4*)(er + p * ESV_PART + 4);
            q0.x += a0.x; q0.y += a0.y; q0.z += a0.z; q0.w += a0.w;
            q1.x += a1.x; q1.y += a1.y; q1.z += a1.z; q1.w += a1.w;
        }
    }
    float4 e0, e1;
    e0.x = __expf(q0.x); e0.y = __expf(q0.y); e0.z = __expf(q0.z); e0.w = __expf(q0.w);
    e1.x = __expf(q1.x); e1.y = __expf(q1.y); e1.z = __expf(q1.z); e1.w = __expf(q1.w);
#pragma unroll 4
    for (int t = 0; t < TOPICS; ++t) {
        float inv = 1.0f / lsum[b * TOPICS + t];
        float o0, o1, o2, o3, o4, o5, o6, o7;
        if (c != 0.f) {
            const float* gr = eb + (size_t)t * VOCAB + v0;
            float4 g0 = *(const float4*)gr;
            float4 g1 = *(const float4*)(gr + 4);
            o0 = e0.x * g0.x * inv; o1 = e0.y * g0.y * inv;
            o2 = e0.z * g0.z * inv; o3 = e0.w * g0.w * inv;
            o4 = e1.x * g1.x * inv; o5 = e1.y * g1.y * inv;
            o6 = e1.z * g1.z * inv; o7 = e1.w * g1.w * inv;
        } else {
            o0 = e0.x * inv; o1 = e0.y * inv; o2 = e0.z * inv; o3 = e0.w * inv;
            o4 = e1.x * inv; o5 = e1.y * inv; o6 = e1.z * inv; o7 = e1.w * inv;
        }
        size_t off = (size_t)b * TOPICS * VOCAB + (size_t)t * VOCAB + v0;
        if constexpr (F32) {
            float4 s0 = {o0, o1, o2, o3}, s1 = {o4, o5, o6, o7};
            *(float4*)((float*)dout + off) = s0;
            *(float4*)((float*)dout + off + 4) = s1;
        } else {
            uint4 st;
            st.x = (u32)f2bf(o0) | ((u32)f2bf(o1) << 16);
            st.y = (u32)f2bf(o2) | ((u32)f2bf(o3) << 16);
            st.z = (u32)f2bf(o4) | ((u32)f2bf(o5) << 16);
            st.w = (u32)f2bf(o6) | ((u32)f2bf(o7) << 16);
            *(uint4*)((u16*)dout + off) = st;
        }
    }
}
__global__ __launch_bounds__(256)
void k_write(const int* __restrict__ flag, const float* __restrict__ esv4,
             const float* __restrict__ eb, const float* __restrict__ coeff,
             const float* __restrict__ lsum, void* dout) {
    if (*flag) write_body<true>(esv4, eb, coeff, lsum, dout);
    else       write_body<false>(esv4, eb, coeff, lsum, dout);
}

extern "C" void kernel_launch(void* const* d_in, const int* in_sizes, int n_in,
                              void* d_out, int out_size, void* d_ws, size_t ws_size,
                              hipStream_t stream) {
    const void* xin  = d_in[0];
    const void* h0   = d_in[1];
    const void* Wxh  = d_in[2];
    const void* Whh  = d_in[3];
    const void* bk   = d_in[4];
    const void* Wv   = d_in[5];
    const void* beta = d_in[6];

    char* ws = (char*)d_ws;
    int*   flag   = (int*)  (ws + 0);
    float* coeff  = (float*)(ws + 256);
    float* lsum   = (float*)(ws + 1024);      // 1280 f -> ends 6144
    float* ns_f32 = (float*)(ws + 8192);      // 256 KiB -> ends 270336
    float* eb     = (float*)(ws + 270336);    // 2.56 MB -> ends 2830336
    float* esv4   = (float*)(ws + 2830336);   // 4 x 8.192 MB -> ends 35598336

    k_init <<<320, 256, 0, stream>>>(beta, flag, lsum, eb);
    k_state<<<256, 256, 0, stream>>>(flag, xin, h0, Wxh, Whh, ns_f32, d_out);
    k_bern <<<64, 64, 0, stream>>>(flag, ns_f32, bk, coeff);
    k_sv   <<<500, 256, 0, stream>>>(flag, ns_f32, Wv, d_out, esv4);
    k_sum  <<<dim3(16, 64), 256, 0, stream>>>(flag, esv4, eb, coeff, lsum);
    k_write<<<dim3(16, 64), 256, 0, stream>>>(flag, esv4, eb, coeff, lsum, d_out);
}

// Round 8
// 464.333 us; speedup vs baseline: 1.1913x; 1.0417x over previous
//
#include <hip/hip_runtime.h>
#include <cstdint>
#include <cstddef>

typedef unsigned int u32;
typedef unsigned short u16;

#define NB 64
#define DIN 512
#define UNITS 1024
#define TOPICS 20
#define VOCAB 32000
#define NS_OFF ((size_t)NB * TOPICS * VOCAB)
#define ESV_PART ((size_t)NB * VOCAB)    // floats per k-partial buffer

typedef __attribute__((ext_vector_type(8))) short s16x8;
typedef __attribute__((ext_vector_type(4))) float f32x4;

// ---------- bf16 helpers ----------
__device__ __forceinline__ float bf2f(u16 h) {
    union { u32 u; float f; } c; c.u = ((u32)h) << 16; return c.f;
}
__device__ __forceinline__ u16 f2bf(float f) {
    union { float f; u32 u; } c; c.f = f;
    u32 r = c.u + 0x7FFFu + ((c.u >> 16) & 1u);   // RNE
    return (u16)(r >> 16);
}
template<bool F32>
__device__ __forceinline__ float ldv(const void* p, size_t i) {
    if constexpr (F32) return ((const float*)p)[i];
    else return bf2f(((const u16*)p)[i]);
}
__device__ __forceinline__ float ldr(const void* p, size_t i, bool f32) {
    return f32 ? ((const float*)p)[i] : bf2f(((const u16*)p)[i]);
}

// ---------- threefry2x32-20, key (0,42), partitionable counts (0,i) ----------
__device__ __forceinline__ u32 threefry_bits_partitionable(u32 i) {
    const u32 ks0 = 0u, ks1 = 42u, ks2 = 0u ^ 42u ^ 0x1BD11BDAu;
    u32 x0 = 0u + ks0, x1 = i + ks1;
#define TF_R(r) { x0 += x1; x1 = (x1 << r) | (x1 >> (32 - r)); x1 ^= x0; }
    TF_R(13) TF_R(15) TF_R(26) TF_R(6)
    x0 += ks1; x1 += ks2 + 1u;
    TF_R(17) TF_R(29) TF_R(16) TF_R(24)
    x0 += ks2; x1 += ks0 + 2u;
    TF_R(13) TF_R(15) TF_R(26) TF_R(6)
    x0 += ks0; x1 += ks1 + 3u;
    TF_R(17) TF_R(29) TF_R(16) TF_R(24)
    x0 += ks1; x1 += ks2 + 4u;
    TF_R(13) TF_R(15) TF_R(26) TF_R(6)
    x0 += ks2; x1 += ks0 + 5u;
#undef TF_R
    return x0 ^ x1;
}

// ---------- init: self-detect dtype, eb = exp(beta), zero lsum, publish flag ----------
__global__ __launch_bounds__(256)
void k_init(const void* __restrict__ beta, int* __restrict__ flag,
            float* __restrict__ lsum, float* __restrict__ eb) {
    int tid = threadIdx.x, lane = tid & 63, w = tid >> 6;
    __shared__ int cnt_s[4];
    int cnt = 0;
    const u32* braw = (const u32*)beta;
    for (int i = tid; i < 1024; i += 256) {
        u32 x = braw[i];
        u32 e = (x >> 7) & 0xFFu;
        cnt += (e >= 110u && e <= 132u) ? 1 : 0;
    }
    for (int off = 32; off; off >>= 1) cnt += __shfl_down(cnt, off, 64);
    if (lane == 0) cnt_s[w] = cnt;
    __syncthreads();
    int total = cnt_s[0] + cnt_s[1] + cnt_s[2] + cnt_s[3];
    bool f32 = total < 512;

    size_t base = (size_t)blockIdx.x * 2000;
    for (int i = tid; i < 2000; i += 256)
        eb[base + i] = __expf(ldr(beta, base + i, f32));

    if (blockIdx.x == 0) {
        for (int i = tid; i < NB * TOPICS; i += 256) lsum[i] = 0.f;
        if (tid == 0) flag[0] = f32 ? 1 : 0;
    }
}

// ---------- A: next_state partials. grid 512 = 64b x 4 u-quarter x 2 k-half ----
// K-split (flattened K = [x 0..512 | h 0..1024] = 1536; half = 768) doubles
// waves/CU (4 -> 8) and halves the per-thread load chain. Deterministic
// p0+p1 sum happens in k_bern (also writes ns to dout there).
template<bool F32>
__device__ void state_body(const void* xin, const void* h0, const void* Wxh,
                           const void* Whh, float* ns_p) {
    __shared__ float lx[768];
    int bid  = blockIdx.x;
    int b    = bid >> 3;
    int uq   = (bid >> 1) & 3;
    int half = bid & 1;
    int u = (uq << 8) | threadIdx.x;
    for (int i = threadIdx.x; i < 768; i += 256) {
        int kk = half * 768 + i;
        lx[i] = (kk < DIN) ? ldv<F32>(xin, (size_t)b * DIN + kk)
                           : ldv<F32>(h0,  (size_t)b * UNITS + (kk - DIN));
    }
    __syncthreads();
    float acc = 0.f;
    if (half == 0) {
#pragma unroll 8
        for (int k = 0; k < DIN; ++k) acc += lx[k] * ldv<F32>(Wxh, (size_t)k * UNITS + u);
#pragma unroll 8
        for (int k = 0; k < 256; ++k) acc += lx[DIN + k] * ldv<F32>(Whh, (size_t)k * UNITS + u);
    } else {
#pragma unroll 8
        for (int k = 0; k < 768; ++k) acc += lx[k] * ldv<F32>(Whh, (size_t)(256 + k) * UNITS + u);
    }
    ns_p[half * (NB * UNITS) + b * UNITS + u] = acc;
}
__global__ __launch_bounds__(256)
void k_state(const int* __restrict__ flag, const void* xin, const void* h0,
             const void* Wxh, const void* Whh, float* __restrict__ ns_p) {
    if (*flag) state_body<true>(xin, h0, Wxh, Whh, ns_p);
    else       state_body<false>(xin, h0, Wxh, Whh, ns_p);
}

// ---------- B: sum partials -> ns_f32 + dout ns; coeff = 1 - bernoulli ----------
template<bool F32>
__device__ void bern_body(const float* ns_p, const void* bk, float* coeff,
                          float* ns_f32, void* dout) {
    int b = blockIdx.x, lane = threadIdx.x;
    float s = 0.f;
#pragma unroll
    for (int i = 0; i < UNITS / 64; ++i) {
        int k = lane + (i << 6);
        int idx = b * UNITS + k;
        float v = ns_p[idx] + ns_p[NB * UNITS + idx];
        ns_f32[idx] = v;
        if constexpr (F32) ((float*)dout)[NS_OFF + idx] = v;
        else               ((u16*)dout)[NS_OFF + idx]   = f2bf(v);
        s += v * ldv<F32>(bk, k);
    }
    for (int off = 32; off; off >>= 1) s += __shfl_down(s, off, 64);
    if (lane == 0) {
        float sp = log1pf(expf(s));              // softplus
        float p  = 1.f / (1.f + expf(-sp));      // sigmoid
        u32 bits = threefry_bits_partitionable((u32)b);
        union { u32 u; float f; } c; c.u = (bits >> 9) | 0x3f800000u;
        float uni = c.f - 1.0f;
        coeff[b] = (uni < p) ? 0.f : 1.f;        // (1 - sample)
    }
}
__global__ __launch_bounds__(64)
void k_bern(const int* __restrict__ flag, const float* __restrict__ ns_p,
            const void* bk, float* __restrict__ coeff,
            float* __restrict__ ns_f32, void* dout) {
    if (*flag) bern_body<true>(ns_p, bk, coeff, ns_f32, dout);
    else       bern_body<false>(ns_p, bk, coeff, ns_f32, dout);
}

// ============================================================================
// C: logit partials. esv4[kb][b][v] = ns[b][kb*256:(kb+1)*256] @ Wv[...][v]
//
// ROUND-8: 4 dispatches (kb=0..3), each 500 blocks (full GPU; r6 showed
// 250-block dispatches lose 1.55x BW) x v-tile 64 x K=256. Purpose:
// (a) per-dispatch ~30us lowers the top-5 visibility floor from 126us to
//     ~35us -> the constant 356us of hidden kernels finally decomposes;
// (b) 128B-chunk pattern measured fastest of all variants (r4: 644 GB/s).
// Structure = r7's proven one (plain loads -> reg -> LDS dbuf, counted
// vmcnt, A straight from global/L2). Per step: 1 B-load + 4 A-loads.
// Swizzle: B src chunk c^(k>>3), read slot ((col>>3)^g) -- r7-verified.
// f32 path: VALU tile, K-quarter [kb*256,+256) -> partial kb (both paths
// now write 4 partials; downstream sums unconditionally).
// ============================================================================
#define PAD 68
#define SV_BB 4096                        // one B stage: 32k x 64v bf16
#define SV_SMEM_BYTES 34816               // f32 path needs 2*64*PAD*4

__device__ void sv_mfma_body(const short* __restrict__ ns16,
                             const short* __restrict__ Wv,
                             float* __restrict__ esv4, char* smem,
                             int pos, int kb) {
    const int tid  = threadIdx.x;
    const int lane = tid & 63;
    const int wn   = tid >> 6;       // wave 0..3
    const int g    = lane >> 4;      // k-group 0..3
    const int l15  = lane & 15;

    const int v0 = pos * 64;
    const int kbase0 = kb * 256;

    // B src: thread stages k-row tid>>3 (0..31), chunk (tid&7)^((tid>>3)>>3)
    const int bk_ = tid >> 3, bc_ = tid & 7;
    const short* bsrc = Wv + (size_t)(kbase0 + bk_) * VOCAB + v0
                      + ((bc_ ^ (bk_ >> 3)) << 3);
    // A src: frag mf reads row mf*16+l15, k-run kbase0 + t*32 + g*8
    const short* as0 = ns16 + (size_t)(l15     ) * UNITS + kbase0 + g * 8;
    const short* as1 = ns16 + (size_t)(l15 + 16) * UNITS + kbase0 + g * 8;
    const short* as2 = ns16 + (size_t)(l15 + 32) * UNITS + kbase0 + g * 8;
    const short* as3 = ns16 + (size_t)(l15 + 48) * UNITS + kbase0 + g * 8;

    float4 bE, bO;
    s16x8  aE0, aE1, aE2, aE3;
    s16x8  aO0, aO1, aO2, aO3;

    f32x4 acc[4];
#pragma unroll
    for (int m = 0; m < 4; ++m) acc[m] = (f32x4){0.f, 0.f, 0.f, 0.f};

#define LOADB(T, R)  { R = *(const float4*)(bsrc + (size_t)(T) * 32 * VOCAB); }
#define LOADA(T, A0, A1, A2, A3) {                                        \
    int ko = (T) * 32;                                                    \
    A0 = *(const s16x8*)(as0 + ko); A1 = *(const s16x8*)(as1 + ko);       \
    A2 = *(const s16x8*)(as2 + ko); A3 = *(const s16x8*)(as3 + ko); }
#define WRITEB(BUF, R)  { ((float4*)(smem + (BUF) * SV_BB))[tid] = R; }
#define COMPUTE(BUF, A0, A1, A2, A3) {                                    \
    const short* Bs = (const short*)(smem + (BUF) * SV_BB);               \
    int col = wn * 16 + l15;                                              \
    int b0  = (((col >> 3) ^ g) << 3) + (col & 7);                        \
    s16x8 bf;                                                             \
    _Pragma("unroll")                                                     \
    for (int e = 0; e < 8; ++e) bf[e] = Bs[(g * 8 + e) * 64 + b0];        \
    acc[0] = __builtin_amdgcn_mfma_f32_16x16x32_bf16(A0, bf, acc[0], 0, 0, 0); \
    acc[1] = __builtin_amdgcn_mfma_f32_16x16x32_bf16(A1, bf, acc[1], 0, 0, 0); \
    acc[2] = __builtin_amdgcn_mfma_f32_16x16x32_bf16(A2, bf, acc[2], 0, 0, 0); \
    acc[3] = __builtin_amdgcn_mfma_f32_16x16x32_bf16(A3, bf, acc[3], 0, 0, 0); }
#define VMW(N)  asm volatile("s_waitcnt vmcnt(" #N ")" ::: "memory");
#define LGK0    asm volatile("s_waitcnt lgkmcnt(0)" ::: "memory");
#define BAR     __builtin_amdgcn_s_barrier();

    // prologue: B(0),A(0),B(1) -> 6 outstanding; keep A(0)+B(1)=5
    LOADB(0, bE)
    LOADA(0, aE0, aE1, aE2, aE3)
    LOADB(1, bO)
    VMW(5)
    WRITEB(0, bE)
    LGK0

    // step T: issue B(T+2),A(T+1); BAR; keep B(T+2)+A(T+1)=5 -> vmcnt(5);
    // write B(T+1); LGK0; compute(T)
    // T=0
    LOADB(2, bE)  LOADA(1, aO0, aO1, aO2, aO3)
    BAR  VMW(5)  WRITEB(1, bO)  LGK0
    COMPUTE(0, aE0, aE1, aE2, aE3)
    // T=1
    LOADB(3, bO)  LOADA(2, aE0, aE1, aE2, aE3)
    BAR  VMW(5)  WRITEB(0, bE)  LGK0
    COMPUTE(1, aO0, aO1, aO2, aO3)
    // T=2
    LOADB(4, bE)  LOADA(3, aO0, aO1, aO2, aO3)
    BAR  VMW(5)  WRITEB(1, bO)  LGK0
    COMPUTE(2, aE0, aE1, aE2, aE3)
    // T=3
    LOADB(5, bO)  LOADA(4, aE0, aE1, aE2, aE3)
    BAR  VMW(5)  WRITEB(0, bE)  LGK0
    COMPUTE(3, aO0, aO1, aO2, aO3)
    // T=4
    LOADB(6, bE)  LOADA(5, aO0, aO1, aO2, aO3)
    BAR  VMW(5)  WRITEB(1, bO)  LGK0
    COMPUTE(4, aE0, aE1, aE2, aE3)
    // T=5
    LOADB(7, bO)  LOADA(6, aE0, aE1, aE2, aE3)
    BAR  VMW(5)  WRITEB(0, bE)  LGK0
    COMPUTE(5, aO0, aO1, aO2, aO3)
    // T=6: no B(8); outstanding A(7)4+B(7)1+A(6)4 -> keep A(7)=4
    LOADA(7, aO0, aO1, aO2, aO3)
    BAR  VMW(4)  WRITEB(1, bO)  LGK0
    COMPUTE(6, aE0, aE1, aE2, aE3)
    // T=7
    BAR  VMW(0)
    COMPUTE(7, aO0, aO1, aO2, aO3)

#undef LOADB
#undef LOADA
#undef WRITEB
#undef COMPUTE
#undef VMW
#undef LGK0
#undef BAR

    // epilogue: raw logit partial. C/D: row=(lane>>4)*4+r, col=l15
    float* dst = esv4 + (size_t)kb * ESV_PART + v0;
    const int col = wn * 16 + l15;
#pragma unroll
    for (int mf = 0; mf < 4; ++mf)
#pragma unroll
        for (int r = 0; r < 4; ++r) {
            int b = mf * 16 + (lane >> 4) * 4 + r;
            dst[(size_t)b * VOCAB + col] = acc[mf][r];
        }
}

__device__ void sv_f32_body(const float* __restrict__ ns, const float* __restrict__ Wv,
                            float* __restrict__ esv4, float* As, float* Bs,
                            int pos, int kb) {
    int tid = threadIdx.x;
    int vt = tid & 7;           // 8 v-threads x 8 v = 64 v
    int bg = tid >> 3;          // 32 groups x 2 b = 64 b
    int v0 = pos * 64;
    float acc[2][8];
#pragma unroll
    for (int r = 0; r < 2; ++r)
#pragma unroll
        for (int j = 0; j < 8; ++j) acc[r][j] = 0.f;

    for (int k0 = kb * 256; k0 < kb * 256 + 256; k0 += 64) {
        __syncthreads();
        for (int e = tid; e < 1024; e += 256) {      // stage A: ns[64b][64k]
            int row = e >> 4, c4 = e & 15;
            *(float4*)&As[row * PAD + c4 * 4] =
                *(const float4*)&ns[row * UNITS + k0 + c4 * 4];
        }
        for (int e = tid; e < 1024; e += 256) {      // stage B: Wv[64k][64v]
            int row = e >> 4, c4 = e & 15;
            *(float4*)&Bs[row * PAD + c4 * 4] =
                *(const float4*)(Wv + (size_t)(k0 + row) * VOCAB + v0 + c4 * 4);
        }
        __syncthreads();
#pragma unroll 4
        for (int u = 0; u < 64; u += 4) {
            float4 a0 = *(float4*)&As[(bg * 2 + 0) * PAD + u];
            float4 a1 = *(float4*)&As[(bg * 2 + 1) * PAD + u];
            float aa0[4] = {a0.x, a0.y, a0.z, a0.w};
            float aa1[4] = {a1.x, a1.y, a1.z, a1.w};
#pragma unroll
            for (int uu = 0; uu < 4; ++uu) {
                float4 b0 = *(float4*)&Bs[(u + uu) * PAD + vt * 8];
                float4 b1 = *(float4*)&Bs[(u + uu) * PAD + vt * 8 + 4];
                float bb[8] = {b0.x, b0.y, b0.z, b0.w, b1.x, b1.y, b1.z, b1.w};
#pragma unroll
                for (int j = 0; j < 8; ++j) {
                    acc[0][j] = fmaf(aa0[uu], bb[j], acc[0][j]);
                    acc[1][j] = fmaf(aa1[uu], bb[j], acc[1][j]);
                }
            }
        }
    }
    // raw logit partial kb
    float* base = esv4 + (size_t)kb * ESV_PART;
#pragma unroll
    for (int r = 0; r < 2; ++r) {
        float4 e0 = {acc[r][0], acc[r][1], acc[r][2], acc[r][3]};
        float4 e1 = {acc[r][4], acc[r][5], acc[r][6], acc[r][7]};
        float* dst = base + (size_t)(bg * 2 + r) * VOCAB + v0 + vt * 8;
        *(float4*)dst = e0;
        *(float4*)(dst + 4) = e1;
    }
}

__global__ __launch_bounds__(256, 3)
void k_sv(const int* __restrict__ flag, const float* __restrict__ ns,
          const void* Wv, const void* dout, float* __restrict__ esv4, int kb) {
    __shared__ __align__(16) char smem[SV_SMEM_BYTES];
    // bijective XCD-chunked remap over 500
    int lin = blockIdx.x;
    int xcd = lin & 7, idx = lin >> 3;
    int pos = (xcd < 4) ? xcd * 63 + idx : 252 + (xcd - 4) * 62 + idx;
    if (*flag) {
        float* As = (float*)smem;
        sv_f32_body(ns, (const float*)Wv, esv4, As, As + 64 * PAD, pos, kb);
    } else {
        sv_mfma_body((const short*)dout + NS_OFF, (const short*)Wv, esv4, smem,
                     pos, kb);
    }
}

// ---------- D1: lsum[b][t] = sum_v exp(sum_kb p_kb) * (c ? eb[t][v] : 1) ----------
__global__ __launch_bounds__(256)
void k_sum(const float* __restrict__ esv4, const float* __restrict__ eb,
           const float* __restrict__ coeff, float* __restrict__ lsum) {
    int b = blockIdx.y, tid = threadIdx.x;
    float c = coeff[b];
    const float4* P0 = (const float4*)(esv4 + (size_t)b * VOCAB);
    const float4* P1 = (const float4*)(esv4 + ESV_PART + (size_t)b * VOCAB);
    const float4* P2 = (const float4*)(esv4 + 2 * ESV_PART + (size_t)b * VOCAB);
    const float4* P3 = (const float4*)(esv4 + 3 * ESV_PART + (size_t)b * VOCAB);
    int i0 = blockIdx.x * 256 + tid;
    __shared__ float red[4][TOPICS];
    int lane = tid & 63, w = tid >> 6;

    if (c != 0.f) {
        float acc[TOPICS];
#pragma unroll
        for (int t = 0; t < TOPICS; ++t) acc[t] = 0.f;
        for (int i = i0; i < VOCAB / 4; i += 4096) {
            float4 q = P0[i];
            float4 a = P1[i], d = P2[i], h = P3[i];
            q.x += a.x + d.x + h.x; q.y += a.y + d.y + h.y;
            q.z += a.z + d.z + h.z; q.w += a.w + d.w + h.w;
            float4 e;
            e.x = __expf(q.x); e.y = __expf(q.y);
            e.z = __expf(q.z); e.w = __expf(q.w);
#pragma unroll
            for (int t = 0; t < TOPICS; ++t) {
                float4 g = *(const float4*)(eb + (size_t)t * VOCAB + i * 4);
                acc[t] += e.x * g.x + e.y * g.y + e.z * g.z + e.w * g.w;
            }
        }
#pragma unroll
        for (int t = 0; t < TOPICS; ++t) {
            float v = acc[t];
            for (int off = 32; off; off >>= 1) v += __shfl_down(v, off, 64);
            if (lane == 0) red[w][t] = v;
        }
        __syncthreads();
        if (tid < TOPICS) {
            float s = red[0][tid] + red[1][tid] + red[2][tid] + red[3][tid];
            atomicAdd(&lsum[b * TOPICS + tid], s);
        }
    } else {
        float a = 0.f;
        for (int i = i0; i < VOCAB / 4; i += 4096) {
            float4 q = P0[i];
            float4 x = P1[i], d = P2[i], h = P3[i];
            q.x += x.x + d.x + h.x; q.y += x.y + d.y + h.y;
            q.z += x.z + d.z + h.z; q.w += x.w + d.w + h.w;
            a += __expf(q.x) + __expf(q.y) + __expf(q.z) + __expf(q.w);
        }
        for (int off = 32; off; off >>= 1) a += __shfl_down(a, off, 64);
        if (lane == 0) red[w][0] = a;
        __syncthreads();
        if (tid < TOPICS) {
            float s = red[0][0] + red[1][0] + red[2][0] + red[3][0];
            atomicAdd(&lsum[b * TOPICS + tid], s);
        }
    }
}

// ---------- D2: out[b][t][v] = exp(sum_kb p_kb) * (c ? eb[t][v] : 1) / lsum[b][t] ----------
template<bool F32>
__device__ void write_body(const float* esv4, const float* eb, const float* coeff,
                           const float* lsum, void* dout) {
    int b = blockIdx.y, tid = threadIdx.x;
    int v0 = blockIdx.x * 2048 + tid * 8;
    if (v0 >= VOCAB) return;
    float c = coeff[b];
    const float* er = esv4 + (size_t)b * VOCAB + v0;
    float4 q0 = *(const float4*)er;
    float4 q1 = *(const float4*)(er + 4);
#pragma unroll
    for (int p = 1; p < 4; ++p) {
        float4 a0 = *(const float4*)(er + p * ESV_PART);
        float4 a1 = *(const float4*)(er + p * ESV_PART + 4);
        q0.x += a0.x; q0.y += a0.y; q0.z += a0.z; q0.w += a0.w;
        q1.x += a1.x; q1.y += a1.y; q1.z += a1.z; q1.w += a1.w;
    }
    float4 e0, e1;
    e0.x = __expf(q0.x); e0.y = __expf(q0.y); e0.z = __expf(q0.z); e0.w = __expf(q0.w);
    e1.x = __expf(q1.x); e1.y = __expf(q1.y); e1.z = __expf(q1.z); e1.w = __expf(q1.w);
#pragma unroll 4
    for (int t = 0; t < TOPICS; ++t) {
        float inv = 1.0f / lsum[b * TOPICS + t];
        float o0, o1, o2, o3, o4, o5, o6, o7;
        if (c != 0.f) {
            const float* gr = eb + (size_t)t * VOCAB + v0;
            float4 g0 = *(const float4*)gr;
            float4 g1 = *(const float4*)(gr + 4);
            o0 = e0.x * g0.x * inv; o1 = e0.y * g0.y * inv;
            o2 = e0.z * g0.z * inv; o3 = e0.w * g0.w * inv;
            o4 = e1.x * g1.x * inv; o5 = e1.y * g1.y * inv;
            o6 = e1.z * g1.z * inv; o7 = e1.w * g1.w * inv;
        } else {
            o0 = e0.x * inv; o1 = e0.y * inv; o2 = e0.z * inv; o3 = e0.w * inv;
            o4 = e1.x * inv; o5 = e1.y * inv; o6 = e1.z * inv; o7 = e1.w * inv;
        }
        size_t off = (size_t)b * TOPICS * VOCAB + (size_t)t * VOCAB + v0;
        if constexpr (F32) {
            float4 s0 = {o0, o1, o2, o3}, s1 = {o4, o5, o6, o7};
            *(float4*)((float*)dout + off) = s0;
            *(float4*)((float*)dout + off + 4) = s1;
        } else {
            uint4 st;
            st.x = (u32)f2bf(o0) | ((u32)f2bf(o1) << 16);
            st.y = (u32)f2bf(o2) | ((u32)f2bf(o3) << 16);
            st.z = (u32)f2bf(o4) | ((u32)f2bf(o5) << 16);
            st.w = (u32)f2bf(o6) | ((u32)f2bf(o7) << 16);
            *(uint4*)((u16*)dout + off) = st;
        }
    }
}
__global__ __launch_bounds__(256)
void k_write(const int* __restrict__ flag, const float* __restrict__ esv4,
             const float* __restrict__ eb, const float* __restrict__ coeff,
             const float* __restrict__ lsum, void* dout) {
    if (*flag) write_body<true>(esv4, eb, coeff, lsum, dout);
    else       write_body<false>(esv4, eb, coeff, lsum, dout);
}

extern "C" void kernel_launch(void* const* d_in, const int* in_sizes, int n_in,
                              void* d_out, int out_size, void* d_ws, size_t ws_size,
                              hipStream_t stream) {
    const void* xin  = d_in[0];
    const void* h0   = d_in[1];
    const void* Wxh  = d_in[2];
    const void* Whh  = d_in[3];
    const void* bk   = d_in[4];
    const void* Wv   = d_in[5];
    const void* beta = d_in[6];

    char* ws = (char*)d_ws;
    int*   flag   = (int*)  (ws + 0);
    float* coeff  = (float*)(ws + 256);
    float* lsum   = (float*)(ws + 1024);      // 1280 f -> ends 6144
    float* ns_f32 = (float*)(ws + 8192);      // 256 KiB -> ends 270336
    float* eb     = (float*)(ws + 270336);    // 2.56 MB -> ends 2830336
    float* esv4   = (float*)(ws + 2830336);   // 4 x 8.192 MB -> ends 35598336
    // ns partials alias the esv4 region head (consumed by k_bern before k_sv)
    float* ns_p   = esv4;                     // 2 x 256 KiB

    k_init <<<320, 256, 0, stream>>>(beta, flag, lsum, eb);
    k_state<<<512, 256, 0, stream>>>(flag, xin, h0, Wxh, Whh, ns_p);
    k_bern <<<64, 64, 0, stream>>>(flag, ns_p, bk, coeff, ns_f32, d_out);
    k_sv   <<<500, 256, 0, stream>>>(flag, ns_f32, Wv, d_out, esv4, 0);
    k_sv   <<<500, 256, 0, stream>>>(flag, ns_f32, Wv, d_out, esv4, 1);
    k_sv   <<<500, 256, 0, stream>>>(flag, ns_f32, Wv, d_out, esv4, 2);
    k_sv   <<<500, 256, 0, stream>>>(flag, ns_f32, Wv, d_out, esv4, 3);
    k_sum  <<<dim3(16, 64), 256, 0, stream>>>(esv4, eb, coeff, lsum);
    k_write<<<dim3(16, 64), 256, 0, stream>>>(flag, esv4, eb, coeff, lsum, d_out);
}

// Round 9
// 406.722 us; speedup vs baseline: 1.3600x; 1.1416x over previous
//
#include <hip/hip_runtime.h>
#include <cstdint>
#include <cstddef>

typedef unsigned int u32;
typedef unsigned short u16;

#define NB 64
#define DIN 512
#define UNITS 1024
#define TOPICS 20
#define VOCAB 32000
#define NS_OFF ((size_t)NB * TOPICS * VOCAB)
#define ESV_PART ((size_t)NB * VOCAB)    // floats per k-partial buffer

typedef __attribute__((ext_vector_type(8))) short s16x8;
typedef __attribute__((ext_vector_type(4))) float f32x4;

// ---------- bf16 helpers ----------
__device__ __forceinline__ float bf2f(u16 h) {
    union { u32 u; float f; } c; c.u = ((u32)h) << 16; return c.f;
}
__device__ __forceinline__ u16 f2bf(float f) {
    union { float f; u32 u; } c; c.f = f;
    u32 r = c.u + 0x7FFFu + ((c.u >> 16) & 1u);   // RNE
    return (u16)(r >> 16);
}
template<bool F32>
__device__ __forceinline__ float ldv(const void* p, size_t i) {
    if constexpr (F32) return ((const float*)p)[i];
    else return bf2f(((const u16*)p)[i]);
}
__device__ __forceinline__ float ldr(const void* p, size_t i, bool f32) {
    return f32 ? ((const float*)p)[i] : bf2f(((const u16*)p)[i]);
}

// ---------- local dtype detection (beta[0:1024] words; block-local, L2-hot) ----
__device__ __forceinline__ bool detect_f32(const void* beta) {
    __shared__ int cnt_s[4];
    int tid = threadIdx.x, lane = tid & 63, w = tid >> 6;
    int cnt = 0;
    const u32* braw = (const u32*)beta;
    for (int i = tid; i < 1024; i += 256) {
        u32 e = (braw[i] >> 7) & 0xFFu;
        cnt += (e >= 110u && e <= 132u) ? 1 : 0;
    }
    for (int off = 32; off; off >>= 1) cnt += __shfl_down(cnt, off, 64);
    if (lane == 0) cnt_s[w] = cnt;
    __syncthreads();
    int total = cnt_s[0] + cnt_s[1] + cnt_s[2] + cnt_s[3];
    return total < 512;
}

// ---------- threefry2x32-20, key (0,42), partitionable counts (0,i) ----------
__device__ __forceinline__ u32 threefry_bits_partitionable(u32 i) {
    const u32 ks0 = 0u, ks1 = 42u, ks2 = 0u ^ 42u ^ 0x1BD11BDAu;
    u32 x0 = 0u + ks0, x1 = i + ks1;
#define TF_R(r) { x0 += x1; x1 = (x1 << r) | (x1 >> (32 - r)); x1 ^= x0; }
    TF_R(13) TF_R(15) TF_R(26) TF_R(6)
    x0 += ks1; x1 += ks2 + 1u;
    TF_R(17) TF_R(29) TF_R(16) TF_R(24)
    x0 += ks2; x1 += ks0 + 2u;
    TF_R(13) TF_R(15) TF_R(26) TF_R(6)
    x0 += ks0; x1 += ks1 + 3u;
    TF_R(17) TF_R(29) TF_R(16) TF_R(24)
    x0 += ks1; x1 += ks2 + 4u;
    TF_R(13) TF_R(15) TF_R(26) TF_R(6)
    x0 += ks2; x1 += ks0 + 5u;
#undef TF_R
    return x0 ^ x1;
}

// ---------- A+init fused. grid 832 = 512 state blocks + 320 eb blocks ----------
// State: 64b x 4 u-quarter x 2 k-half partials (r8-verified). Init blocks
// (512..831) compute eb = exp(beta); block 512 zeroes lsum + publishes flag
// (downstream kernels launch after -> stream-ordered visibility).
template<bool F32>
__device__ void state_body(const void* xin, const void* h0, const void* Wxh,
                           const void* Whh, float* ns_p) {
    __shared__ float lx[768];
    int bid  = blockIdx.x;
    int b    = bid >> 3;
    int uq   = (bid >> 1) & 3;
    int half = bid & 1;
    int u = (uq << 8) | threadIdx.x;
    for (int i = threadIdx.x; i < 768; i += 256) {
        int kk = half * 768 + i;
        lx[i] = (kk < DIN) ? ldv<F32>(xin, (size_t)b * DIN + kk)
                           : ldv<F32>(h0,  (size_t)b * UNITS + (kk - DIN));
    }
    __syncthreads();
    float acc = 0.f;
    if (half == 0) {
#pragma unroll 8
        for (int k = 0; k < DIN; ++k) acc += lx[k] * ldv<F32>(Wxh, (size_t)k * UNITS + u);
#pragma unroll 8
        for (int k = 0; k < 256; ++k) acc += lx[DIN + k] * ldv<F32>(Whh, (size_t)k * UNITS + u);
    } else {
#pragma unroll 8
        for (int k = 0; k < 768; ++k) acc += lx[k] * ldv<F32>(Whh, (size_t)(256 + k) * UNITS + u);
    }
    ns_p[half * (NB * UNITS) + b * UNITS + u] = acc;
}
__global__ __launch_bounds__(256)
void k_state(const void* __restrict__ beta, const void* xin, const void* h0,
             const void* Wxh, const void* Whh, float* __restrict__ ns_p,
             int* __restrict__ flag, float* __restrict__ lsum,
             float* __restrict__ eb) {
    bool f32 = detect_f32(beta);
    int bid = blockIdx.x, tid = threadIdx.x;
    if (bid >= 512) {
        size_t base = (size_t)(bid - 512) * 2000;
        for (int i = tid; i < 2000; i += 256)
            eb[base + i] = __expf(ldr(beta, base + i, f32));
        if (bid == 512) {
            for (int i = tid; i < NB * TOPICS; i += 256) lsum[i] = 0.f;
            if (tid == 0) flag[0] = f32 ? 1 : 0;
        }
        return;
    }
    if (f32) state_body<true>(xin, h0, Wxh, Whh, ns_p);
    else     state_body<false>(xin, h0, Wxh, Whh, ns_p);
}

// ---------- B: sum partials -> ns_f32 + dout ns; coeff = 1 - bernoulli ----------
template<bool F32>
__device__ void bern_body(const float* ns_p, const void* bk, float* coeff,
                          float* ns_f32, void* dout) {
    int b = blockIdx.x, lane = threadIdx.x;
    float s = 0.f;
#pragma unroll
    for (int i = 0; i < UNITS / 64; ++i) {
        int k = lane + (i << 6);
        int idx = b * UNITS + k;
        float v = ns_p[idx] + ns_p[NB * UNITS + idx];
        ns_f32[idx] = v;
        if constexpr (F32) ((float*)dout)[NS_OFF + idx] = v;
        else               ((u16*)dout)[NS_OFF + idx]   = f2bf(v);
        s += v * ldv<F32>(bk, k);
    }
    for (int off = 32; off; off >>= 1) s += __shfl_down(s, off, 64);
    if (lane == 0) {
        float sp = log1pf(expf(s));              // softplus
        float p  = 1.f / (1.f + expf(-sp));      // sigmoid
        u32 bits = threefry_bits_partitionable((u32)b);
        union { u32 u; float f; } c; c.u = (bits >> 9) | 0x3f800000u;
        float uni = c.f - 1.0f;
        coeff[b] = (uni < p) ? 0.f : 1.f;        // (1 - sample)
    }
}
__global__ __launch_bounds__(64)
void k_bern(const int* __restrict__ flag, const float* __restrict__ ns_p,
            const void* bk, float* __restrict__ coeff,
            float* __restrict__ ns_f32, void* dout) {
    if (*flag) bern_body<true>(ns_p, bk, coeff, ns_f32, dout);
    else       bern_body<false>(ns_p, bk, coeff, ns_f32, dout);
}

// ============================================================================
// C: logit partials. esv4[kb][b][v] = ns[b][kb*256:(kb+1)*256] @ Wv[...][v]
// ROUND-9: single dispatch, grid 2000 = 4 kb-quarters x 500 (XCD-swizzled
// within each quarter). Inner structure = r8's verified one (plain loads ->
// reg -> LDS dbuf, counted vmcnt, A straight from global/L2; k_sv wall
// ~0.64 TB/s is pattern-intrinsic and L3 is wiped per-iteration by the
// harness's 656MB re-poison fill, so this is the floor).
// ============================================================================
#define PAD 68
#define SV_BB 4096                        // one B stage: 32k x 64v bf16
#define SV_SMEM_BYTES 34816               // f32 path needs 2*64*PAD*4

__device__ void sv_mfma_body(const short* __restrict__ ns16,
                             const short* __restrict__ Wv,
                             float* __restrict__ esv4, char* smem,
                             int pos, int kb) {
    const int tid  = threadIdx.x;
    const int lane = tid & 63;
    const int wn   = tid >> 6;       // wave 0..3
    const int g    = lane >> 4;      // k-group 0..3
    const int l15  = lane & 15;

    const int v0 = pos * 64;
    const int kbase0 = kb * 256;

    // B src: thread stages k-row tid>>3 (0..31), chunk (tid&7)^((tid>>3)>>3)
    const int bk_ = tid >> 3, bc_ = tid & 7;
    const short* bsrc = Wv + (size_t)(kbase0 + bk_) * VOCAB + v0
                      + ((bc_ ^ (bk_ >> 3)) << 3);
    // A src: frag mf reads row mf*16+l15, k-run kbase0 + t*32 + g*8
    const short* as0 = ns16 + (size_t)(l15     ) * UNITS + kbase0 + g * 8;
    const short* as1 = ns16 + (size_t)(l15 + 16) * UNITS + kbase0 + g * 8;
    const short* as2 = ns16 + (size_t)(l15 + 32) * UNITS + kbase0 + g * 8;
    const short* as3 = ns16 + (size_t)(l15 + 48) * UNITS + kbase0 + g * 8;

    float4 bE, bO;
    s16x8  aE0, aE1, aE2, aE3;
    s16x8  aO0, aO1, aO2, aO3;

    f32x4 acc[4];
#pragma unroll
    for (int m = 0; m < 4; ++m) acc[m] = (f32x4){0.f, 0.f, 0.f, 0.f};

#define LOADB(T, R)  { R = *(const float4*)(bsrc + (size_t)(T) * 32 * VOCAB); }
#define LOADA(T, A0, A1, A2, A3) {                                        \
    int ko = (T) * 32;                                                    \
    A0 = *(const s16x8*)(as0 + ko); A1 = *(const s16x8*)(as1 + ko);       \
    A2 = *(const s16x8*)(as2 + ko); A3 = *(const s16x8*)(as3 + ko); }
#define WRITEB(BUF, R)  { ((float4*)(smem + (BUF) * SV_BB))[tid] = R; }
#define COMPUTE(BUF, A0, A1, A2, A3) {                                    \
    const short* Bs = (const short*)(smem + (BUF) * SV_BB);               \
    int col = wn * 16 + l15;                                              \
    int b0  = (((col >> 3) ^ g) << 3) + (col & 7);                        \
    s16x8 bf;                                                             \
    _Pragma("unroll")                                                     \
    for (int e = 0; e < 8; ++e) bf[e] = Bs[(g * 8 + e) * 64 + b0];        \
    acc[0] = __builtin_amdgcn_mfma_f32_16x16x32_bf16(A0, bf, acc[0], 0, 0, 0); \
    acc[1] = __builtin_amdgcn_mfma_f32_16x16x32_bf16(A1, bf, acc[1], 0, 0, 0); \
    acc[2] = __builtin_amdgcn_mfma_f32_16x16x32_bf16(A2, bf, acc[2], 0, 0, 0); \
    acc[3] = __builtin_amdgcn_mfma_f32_16x16x32_bf16(A3, bf, acc[3], 0, 0, 0); }
#define VMW(N)  asm volatile("s_waitcnt vmcnt(" #N ")" ::: "memory");
#define LGK0    asm volatile("s_waitcnt lgkmcnt(0)" ::: "memory");
#define BAR     __builtin_amdgcn_s_barrier();

    // prologue: B(0),A(0),B(1) -> 6 outstanding; keep A(0)+B(1)=5
    LOADB(0, bE)
    LOADA(0, aE0, aE1, aE2, aE3)
    LOADB(1, bO)
    VMW(5)
    WRITEB(0, bE)
    LGK0

    // step T: issue B(T+2),A(T+1); BAR; vmcnt(5); write B(T+1); LGK0; compute(T)
    // T=0
    LOADB(2, bE)  LOADA(1, aO0, aO1, aO2, aO3)
    BAR  VMW(5)  WRITEB(1, bO)  LGK0
    COMPUTE(0, aE0, aE1, aE2, aE3)
    // T=1
    LOADB(3, bO)  LOADA(2, aE0, aE1, aE2, aE3)
    BAR  VMW(5)  WRITEB(0, bE)  LGK0
    COMPUTE(1, aO0, aO1, aO2, aO3)
    // T=2
    LOADB(4, bE)  LOADA(3, aO0, aO1, aO2, aO3)
    BAR  VMW(5)  WRITEB(1, bO)  LGK0
    COMPUTE(2, aE0, aE1, aE2, aE3)
    // T=3
    LOADB(5, bO)  LOADA(4, aE0, aE1, aE2, aE3)
    BAR  VMW(5)  WRITEB(0, bE)  LGK0
    COMPUTE(3, aO0, aO1, aO2, aO3)
    // T=4
    LOADB(6, bE)  LOADA(5, aO0, aO1, aO2, aO3)
    BAR  VMW(5)  WRITEB(1, bO)  LGK0
    COMPUTE(4, aE0, aE1, aE2, aE3)
    // T=5
    LOADB(7, bO)  LOADA(6, aE0, aE1, aE2, aE3)
    BAR  VMW(5)  WRITEB(0, bE)  LGK0
    COMPUTE(5, aO0, aO1, aO2, aO3)
    // T=6: no B(8); outstanding A(7)4+B(7)1+A(6)4 -> keep A(7)=4
    LOADA(7, aO0, aO1, aO2, aO3)
    BAR  VMW(4)  WRITEB(1, bO)  LGK0
    COMPUTE(6, aE0, aE1, aE2, aE3)
    // T=7
    BAR  VMW(0)
    COMPUTE(7, aO0, aO1, aO2, aO3)

#undef LOADB
#undef LOADA
#undef WRITEB
#undef COMPUTE
#undef VMW
#undef LGK0
#undef BAR

    // epilogue: raw logit partial. C/D: row=(lane>>4)*4+r, col=l15
    float* dst = esv4 + (size_t)kb * ESV_PART + v0;
    const int col = wn * 16 + l15;
#pragma unroll
    for (int mf = 0; mf < 4; ++mf)
#pragma unroll
        for (int r = 0; r < 4; ++r) {
            int b = mf * 16 + (lane >> 4) * 4 + r;
            dst[(size_t)b * VOCAB + col] = acc[mf][r];
        }
}

__device__ void sv_f32_body(const float* __restrict__ ns, const float* __restrict__ Wv,
                            float* __restrict__ esv4, float* As, float* Bs,
                            int pos, int kb) {
    int tid = threadIdx.x;
    int vt = tid & 7;           // 8 v-threads x 8 v = 64 v
    int bg = tid >> 3;          // 32 groups x 2 b = 64 b
    int v0 = pos * 64;
    float acc[2][8];
#pragma unroll
    for (int r = 0; r < 2; ++r)
#pragma unroll
        for (int j = 0; j < 8; ++j) acc[r][j] = 0.f;

    for (int k0 = kb * 256; k0 < kb * 256 + 256; k0 += 64) {
        __syncthreads();
        for (int e = tid; e < 1024; e += 256) {      // stage A: ns[64b][64k]
            int row = e >> 4, c4 = e & 15;
            *(float4*)&As[row * PAD + c4 * 4] =
                *(const float4*)&ns[row * UNITS + k0 + c4 * 4];
        }
        for (int e = tid; e < 1024; e += 256) {      // stage B: Wv[64k][64v]
            int row = e >> 4, c4 = e & 15;
            *(float4*)&Bs[row * PAD + c4 * 4] =
                *(const float4*)(Wv + (size_t)(k0 + row) * VOCAB + v0 + c4 * 4);
        }
        __syncthreads();
#pragma unroll 4
        for (int u = 0; u < 64; u += 4) {
            float4 a0 = *(float4*)&As[(bg * 2 + 0) * PAD + u];
            float4 a1 = *(float4*)&As[(bg * 2 + 1) * PAD + u];
            float aa0[4] = {a0.x, a0.y, a0.z, a0.w};
            float aa1[4] = {a1.x, a1.y, a1.z, a1.w};
#pragma unroll
            for (int uu = 0; uu < 4; ++uu) {
                float4 b0 = *(float4*)&Bs[(u + uu) * PAD + vt * 8];
                float4 b1 = *(float4*)&Bs[(u + uu) * PAD + vt * 8 + 4];
                float bb[8] = {b0.x, b0.y, b0.z, b0.w, b1.x, b1.y, b1.z, b1.w};
#pragma unroll
                for (int j = 0; j < 8; ++j) {
                    acc[0][j] = fmaf(aa0[uu], bb[j], acc[0][j]);
                    acc[1][j] = fmaf(aa1[uu], bb[j], acc[1][j]);
                }
            }
        }
    }
    // raw logit partial kb
    float* base = esv4 + (size_t)kb * ESV_PART;
#pragma unroll
    for (int r = 0; r < 2; ++r) {
        float4 e0 = {acc[r][0], acc[r][1], acc[r][2], acc[r][3]};
        float4 e1 = {acc[r][4], acc[r][5], acc[r][6], acc[r][7]};
        float* dst = base + (size_t)(bg * 2 + r) * VOCAB + v0 + vt * 8;
        *(float4*)dst = e0;
        *(float4*)(dst + 4) = e1;
    }
}

__global__ __launch_bounds__(256, 3)
void k_sv(const int* __restrict__ flag, const float* __restrict__ ns,
          const void* Wv, const void* dout, float* __restrict__ esv4) {
    __shared__ __align__(16) char smem[SV_SMEM_BYTES];
    int lin = blockIdx.x;                     // 0..1999
    int kb  = lin / 500;
    int q   = lin - kb * 500;
    // bijective XCD-chunked remap within each 500-quarter
    int xcd = q & 7, idx = q >> 3;
    int pos = (xcd < 4) ? xcd * 63 + idx : 252 + (xcd - 4) * 62 + idx;
    if (*flag) {
        float* As = (float*)smem;
        sv_f32_body(ns, (const float*)Wv, esv4, As, As + 64 * PAD, pos, kb);
    } else {
        sv_mfma_body((const short*)dout + NS_OFF, (const short*)Wv, esv4, smem,
                     pos, kb);
    }
}

// ---------- D1: lsum[b][t] = sum_v e*(c?eb:1); also stores esv_c = exp(sum p) ----------
__global__ __launch_bounds__(256)
void k_sum(const float* __restrict__ esv4, const float* __restrict__ eb,
           const float* __restrict__ coeff, float* __restrict__ lsum,
           float* __restrict__ esv_c) {
    int b = blockIdx.y, tid = threadIdx.x;
    float c = coeff[b];
    const float4* P0 = (const float4*)(esv4 + (size_t)b * VOCAB);
    const float4* P1 = (const float4*)(esv4 + ESV_PART + (size_t)b * VOCAB);
    const float4* P2 = (const float4*)(esv4 + 2 * ESV_PART + (size_t)b * VOCAB);
    const float4* P3 = (const float4*)(esv4 + 3 * ESV_PART + (size_t)b * VOCAB);
    float4* EC = (float4*)(esv_c + (size_t)b * VOCAB);
    int i0 = blockIdx.x * 256 + tid;
    __shared__ float red[4][TOPICS];
    int lane = tid & 63, w = tid >> 6;

    if (c != 0.f) {
        float acc[TOPICS];
#pragma unroll
        for (int t = 0; t < TOPICS; ++t) acc[t] = 0.f;
        for (int i = i0; i < VOCAB / 4; i += 4096) {
            float4 q = P0[i];
            float4 a = P1[i], d = P2[i], h = P3[i];
            q.x += a.x + d.x + h.x; q.y += a.y + d.y + h.y;
            q.z += a.z + d.z + h.z; q.w += a.w + d.w + h.w;
            float4 e;
            e.x = __expf(q.x); e.y = __expf(q.y);
            e.z = __expf(q.z); e.w = __expf(q.w);
            EC[i] = e;
#pragma unroll
            for (int t = 0; t < TOPICS; ++t) {
                float4 g = *(const float4*)(eb + (size_t)t * VOCAB + i * 4);
                acc[t] += e.x * g.x + e.y * g.y + e.z * g.z + e.w * g.w;
            }
        }
#pragma unroll
        for (int t = 0; t < TOPICS; ++t) {
            float v = acc[t];
            for (int off = 32; off; off >>= 1) v += __shfl_down(v, off, 64);
            if (lane == 0) red[w][t] = v;
        }
        __syncthreads();
        if (tid < TOPICS) {
            float s = red[0][tid] + red[1][tid] + red[2][tid] + red[3][tid];
            atomicAdd(&lsum[b * TOPICS + tid], s);
        }
    } else {
        float a = 0.f;
        for (int i = i0; i < VOCAB / 4; i += 4096) {
            float4 q = P0[i];
            float4 x = P1[i], d = P2[i], h = P3[i];
            q.x += x.x + d.x + h.x; q.y += x.y + d.y + h.y;
            q.z += x.z + d.z + h.z; q.w += x.w + d.w + h.w;
            float4 e;
            e.x = __expf(q.x); e.y = __expf(q.y);
            e.z = __expf(q.z); e.w = __expf(q.w);
            EC[i] = e;
            a += e.x + e.y + e.z + e.w;
        }
        for (int off = 32; off; off >>= 1) a += __shfl_down(a, off, 64);
        if (lane == 0) red[w][0] = a;
        __syncthreads();
        if (tid < TOPICS) {
            float s = red[0][0] + red[1][0] + red[2][0] + red[3][0];
            atomicAdd(&lsum[b * TOPICS + tid], s);
        }
    }
}

// ---------- D2: out[b][t][v] = esv_c[b][v] * (c ? eb[t][v] : 1) / lsum[b][t] ----------
template<bool F32>
__device__ void write_body(const float* esv_c, const float* eb, const float* coeff,
                           const float* lsum, void* dout) {
    int b = blockIdx.y, tid = threadIdx.x;
    int v0 = blockIdx.x * 2048 + tid * 8;
    if (v0 >= VOCAB) return;
    float c = coeff[b];
    const float* er = esv_c + (size_t)b * VOCAB + v0;
    float4 e0 = *(const float4*)er;
    float4 e1 = *(const float4*)(er + 4);
#pragma unroll 4
    for (int t = 0; t < TOPICS; ++t) {
        float inv = 1.0f / lsum[b * TOPICS + t];
        float o0, o1, o2, o3, o4, o5, o6, o7;
        if (c != 0.f) {
            const float* gr = eb + (size_t)t * VOCAB + v0;
            float4 g0 = *(const float4*)gr;
            float4 g1 = *(const float4*)(gr + 4);
            o0 = e0.x * g0.x * inv; o1 = e0.y * g0.y * inv;
            o2 = e0.z * g0.z * inv; o3 = e0.w * g0.w * inv;
            o4 = e1.x * g1.x * inv; o5 = e1.y * g1.y * inv;
            o6 = e1.z * g1.z * inv; o7 = e1.w * g1.w * inv;
        } else {
            o0 = e0.x * inv; o1 = e0.y * inv; o2 = e0.z * inv; o3 = e0.w * inv;
            o4 = e1.x * inv; o5 = e1.y * inv; o6 = e1.z * inv; o7 = e1.w * inv;
        }
        size_t off = (size_t)b * TOPICS * VOCAB + (size_t)t * VOCAB + v0;
        if constexpr (F32) {
            float4 s0 = {o0, o1, o2, o3}, s1 = {o4, o5, o6, o7};
            *(float4*)((float*)dout + off) = s0;
            *(float4*)((float*)dout + off + 4) = s1;
        } else {
            uint4 st;
            st.x = (u32)f2bf(o0) | ((u32)f2bf(o1) << 16);
            st.y = (u32)f2bf(o2) | ((u32)f2bf(o3) << 16);
            st.z = (u32)f2bf(o4) | ((u32)f2bf(o5) << 16);
            st.w = (u32)f2bf(o6) | ((u32)f2bf(o7) << 16);
            *(uint4*)((u16*)dout + off) = st;
        }
    }
}
__global__ __launch_bounds__(256)
void k_write(const int* __restrict__ flag, const float* __restrict__ esv_c,
             const float* __restrict__ eb, const float* __restrict__ coeff,
             const float* __restrict__ lsum, void* dout) {
    if (*flag) write_body<true>(esv_c, eb, coeff, lsum, dout);
    else       write_body<false>(esv_c, eb, coeff, lsum, dout);
}

extern "C" void kernel_launch(void* const* d_in, const int* in_sizes, int n_in,
                              void* d_out, int out_size, void* d_ws, size_t ws_size,
                              hipStream_t stream) {
    const void* xin  = d_in[0];
    const void* h0   = d_in[1];
    const void* Wxh  = d_in[2];
    const void* Whh  = d_in[3];
    const void* bk   = d_in[4];
    const void* Wv   = d_in[5];
    const void* beta = d_in[6];

    char* ws = (char*)d_ws;
    int*   flag   = (int*)  (ws + 0);
    float* coeff  = (float*)(ws + 256);
    float* lsum   = (float*)(ws + 1024);      // 1280 f -> ends 6144
    float* ns_f32 = (float*)(ws + 8192);      // 256 KiB -> ends 270336
    float* eb     = (float*)(ws + 270336);    // 2.56 MB -> ends 2830336
    float* esv4   = (float*)(ws + 2830336);   // 4 x 8.192 MB -> ends 35598336
    float* esv_c  = (float*)(ws + 35598336);  // 8.192 MB -> ends 43790336
    // ns partials alias the esv4 region head (consumed by k_bern before k_sv)
    float* ns_p   = esv4;                     // 2 x 256 KiB

    k_state<<<832, 256, 0, stream>>>(beta, xin, h0, Wxh, Whh, ns_p, flag, lsum, eb);
    k_bern <<<64, 64, 0, stream>>>(flag, ns_p, bk, coeff, ns_f32, d_out);
    k_sv   <<<2000, 256, 0, stream>>>(flag, ns_f32, Wv, d_out, esv4);
    k_sum  <<<dim3(16, 64), 256, 0, stream>>>(esv4, eb, coeff, lsum, esv_c);
    k_write<<<dim3(16, 64), 256, 0, stream>>>(flag, esv_c, eb, coeff, lsum, d_out);
}